// Round 2
// baseline (727.314 us; speedup 1.0000x reference)
//
#include <hip/hip_runtime.h>

using u16 = unsigned short;
using u32 = unsigned int;

typedef short bf16x8 __attribute__((ext_vector_type(8)));
typedef float f32x4 __attribute__((ext_vector_type(4)));

#define HW 3136
#define IMG 56

__device__ __forceinline__ float bf2f(u16 v) {
    union { u32 u; float f; } c; c.u = ((u32)v) << 16; return c.f;
}
__device__ __forceinline__ u16 f2bf(float f) {
    union { float f; u32 u; } c; c.f = f;
    return (u16)((c.u + 0x7fffu + ((c.u >> 16) & 1u)) >> 16);
}
__device__ __forceinline__ int swz8(int r) { return (r ^ (r >> 3)) & 7; }

__device__ __forceinline__ f32x4 mfma16(bf16x8 a, bf16x8 b, f32x4 c) {
    return __builtin_amdgcn_mfma_f32_16x16x32_bf16(a, b, c, 0, 0, 0);
}

// ---------------------------------------------------------------------------
// Generic 128x128-tile GEMM over 1x1-conv shapes. Weights/bias/scale are f32
// (from d_in). act/res/out are f32 or bf16 per flags. Internals: bf16 MFMA,
// f32 accumulate.
//   normal  (swapmode=0): out[m][p] = sum_k W[m][k] * act[k][p]   (m-major out)
//   swapped (swapmode=1): out[p][m] = same product                (p-major out)
// ---------------------------------------------------------------------------
__global__ __launch_bounds__(256) void gemm128(
    const float* __restrict__ w0, const float* __restrict__ w1, const float* __restrict__ w2,
    const float* __restrict__ bb0, const float* __restrict__ bb1, const float* __restrict__ bb2,
    const void* __restrict__ act, int actC, int choff, int K, int actF32,
    void* __restrict__ out, int outLd, int outoff, int swapmode, int outF32,
    const float* __restrict__ scale, const void* __restrict__ res, int resoff, int resF32,
    int gelu)
{
    __shared__ __align__(16) char smem[32768];
    const int tid = threadIdx.x;
    const int lane = tid & 63, wid = tid >> 6;
    const int Pbase = blockIdx.x * 128;
    const int Mbase = blockIdx.y * 128;
    const int bz = blockIdx.z;

    const int sel = Mbase >> 9;
    const float* wsel = (sel == 0) ? w0 : ((sel == 1) ? w1 : w2);
    const float* bsel = (sel == 0) ? bb0 : ((sel == 1) ? bb1 : bb2);
    const int wrow0 = Mbase - sel * 512;

    const long actRow0 = (long)bz * actC + choff;

    f32x4 acc[4][4] = {};

    for (int ko = 0; ko < K; ko += 64) {
        // ---- stage W tile [128][64k] native (f32 -> bf16), chunk-swizzled
        #pragma unroll
        for (int t = 0; t < 4; ++t) {
            int id = tid + t * 256;
            int row = id >> 3, c = id & 7;
            const float* src = wsel + (long)(wrow0 + row) * K + ko + c * 8;
            float4 f0 = *(const float4*)src;
            float4 f1 = *(const float4*)(src + 4);
            u16 tmp[8] = { f2bf(f0.x), f2bf(f0.y), f2bf(f0.z), f2bf(f0.w),
                           f2bf(f1.x), f2bf(f1.y), f2bf(f1.z), f2bf(f1.w) };
            *(uint4*)(smem + row * 128 + ((c ^ swz8(row)) * 16)) = *(uint4*)tmp;
        }
        // ---- stage act tile transposed -> Xt[128p][64k]
        #pragma unroll
        for (int t = 0; t < 4; ++t) {
            int id = tid + t * 256;
            int k = id >> 4, pc = id & 15;
            int p0 = Pbase + pc * 8;
            u16 vals[8];
            if (p0 < HW) {
                if (actF32) {
                    const float* s = (const float*)act + (actRow0 + ko + k) * HW + p0;
                    float4 f0 = *(const float4*)s;
                    float4 f1 = *(const float4*)(s + 4);
                    vals[0] = f2bf(f0.x); vals[1] = f2bf(f0.y);
                    vals[2] = f2bf(f0.z); vals[3] = f2bf(f0.w);
                    vals[4] = f2bf(f1.x); vals[5] = f2bf(f1.y);
                    vals[6] = f2bf(f1.z); vals[7] = f2bf(f1.w);
                } else {
                    *(uint4*)vals = *(const uint4*)((const u16*)act + (actRow0 + ko + k) * HW + p0);
                }
            } else {
                #pragma unroll
                for (int jj = 0; jj < 8; ++jj) vals[jj] = 0;
            }
            #pragma unroll
            for (int jj = 0; jj < 8; ++jj) {
                int p = pc * 8 + jj;
                *(u16*)(smem + 16384 + p * 128 + (((k >> 3) ^ swz8(p)) * 16) + (k & 7) * 2) = vals[jj];
            }
        }
        __syncthreads();

        #pragma unroll
        for (int ks = 0; ks < 2; ++ks) {
            const int ch = ks * 4 + (lane >> 4);
            const int l15 = lane & 15;
            bf16x8 af[4], bfr[4];
            if (!swapmode) {
                #pragma unroll
                for (int rt = 0; rt < 4; ++rt) {
                    int row = (wid >> 1) * 64 + rt * 16 + l15;
                    af[rt] = *(const bf16x8*)(smem + row * 128 + ((ch ^ swz8(row)) * 16));
                }
                #pragma unroll
                for (int ct = 0; ct < 4; ++ct) {
                    int p = (wid & 1) * 64 + ct * 16 + l15;
                    bfr[ct] = *(const bf16x8*)(smem + 16384 + p * 128 + ((ch ^ swz8(p)) * 16));
                }
            } else {
                #pragma unroll
                for (int rt = 0; rt < 4; ++rt) {
                    int p = (wid >> 1) * 64 + rt * 16 + l15;
                    af[rt] = *(const bf16x8*)(smem + 16384 + p * 128 + ((ch ^ swz8(p)) * 16));
                }
                #pragma unroll
                for (int ct = 0; ct < 4; ++ct) {
                    int row = (wid & 1) * 64 + ct * 16 + l15;
                    bfr[ct] = *(const bf16x8*)(smem + row * 128 + ((ch ^ swz8(row)) * 16));
                }
            }
            #pragma unroll
            for (int rt = 0; rt < 4; ++rt)
                #pragma unroll
                for (int ct = 0; ct < 4; ++ct)
                    acc[rt][ct] = mfma16(af[rt], bfr[ct], acc[rt][ct]);
        }
        __syncthreads();
    }

    // ---- epilogue + store
    const int l15 = lane & 15, lg = lane >> 4;
    #pragma unroll
    for (int rt = 0; rt < 4; ++rt) {
      #pragma unroll
      for (int ct = 0; ct < 4; ++ct) {
        #pragma unroll
        for (int r = 0; r < 4; ++r) {
            int m, p;
            if (!swapmode) {
                m = Mbase + (wid >> 1) * 64 + rt * 16 + lg * 4 + r;
                p = Pbase + (wid & 1) * 64 + ct * 16 + l15;
            } else {
                p = Pbase + (wid >> 1) * 64 + rt * 16 + lg * 4 + r;
                m = Mbase + (wid & 1) * 64 + ct * 16 + l15;
            }
            if (p >= HW) continue;
            float v = acc[rt][ct][r] + bsel[m - sel * 512];
            if (gelu)  v = v * 0.5f * (1.0f + erff(v * 0.70710678118f));
            if (scale) v *= scale[outoff + m];
            if (res) {
                long raddr = ((long)(bz * 256 + resoff + m)) * HW + p;
                v += resF32 ? ((const float*)res)[raddr] : bf2f(((const u16*)res)[raddr]);
            }
            long oaddr;
            if (!swapmode) oaddr = ((long)bz * outLd + outoff + m) * HW + p;
            else           oaddr = ((long)bz * HW + p) * (long)outLd + outoff + m;
            if (outF32) ((float*)out)[oaddr] = v;
            else        ((u16*)out)[oaddr] = f2bf(v);
        }
      }
    }
}

// ---------------------------------------------------------------------------
// Axial attention, one block per (b, row-or-col, head). 4 waves.
// Q,K read p-major from qk (bf16 ws; cols [0,512)=Q, [512,1024)=K); V from
// Vx m-major bf16 (branch 0) or p-major cols [1024,1536) of qk (branch 1,
// LDS-transposed). rel is f32 (d_in). Writes the torch raw-reshape scramble
// directly: w' = n*14 + i/4, c = (i%4)*128 + d.
// ---------------------------------------------------------------------------
__global__ __launch_bounds__(256) void attn_kernel(
    const u16* __restrict__ qk, int ldqk,
    const u16* __restrict__ vsrc,
    const float* __restrict__ rel,
    u16* __restrict__ S, int branch)
{
    __shared__ __align__(16) char smem[57856];
    // QT:[0,16K) KT:[16K,32K) V:[32K,48K) P:[49152,57344) RELf32:[57344,57856)
    const int tid = threadIdx.x;
    const int lane = tid & 63, wid = tid >> 6;
    const int rc = blockIdx.x;   // image row (branch 0) / image col (branch 1)
    const int n  = blockIdx.y;
    const int b  = blockIdx.z;

    if (tid < 128) {
        float v = (tid < 112) ? rel[n * HW + tid] : 0.0f;
        *(float*)(smem + 57344 + tid * 4) = v;
    }

    // ---- stage Qt/Kt [64][128] seq-major (zero-padded rows >= 56)
    #pragma unroll
    for (int t = 0; t < 4; ++t) {
        int id = tid + t * 256;
        int i = id >> 4, c = id & 15;
        uint4 v  = make_uint4(0, 0, 0, 0);
        uint4 v2 = make_uint4(0, 0, 0, 0);
        if (i < IMG) {
            long p = (branch == 0) ? ((long)rc * IMG + i) : ((long)i * IMG + rc);
            const u16* src = qk + ((long)b * HW + p) * ldqk + n * 128 + c * 8;
            v  = *(const uint4*)src;
            v2 = *(const uint4*)(src + 512);
        }
        int off = i * 256 + ((c ^ swz8(i)) * 16);
        *(uint4*)(smem + off) = v;
        *(uint4*)(smem + 16384 + off) = v2;
    }

    // ---- stage V [128d][64j] d-major (cols >= 56 zeroed)
    if (branch == 0) {
        #pragma unroll
        for (int t = 0; t < 4; ++t) {
            int id = tid + t * 256;
            int d = id >> 3, c = id & 7;
            uint4 v = make_uint4(0, 0, 0, 0);
            if (c < 7) {
                const u16* src = vsrc + ((long)b * 512 + n * 128 + d) * HW + rc * IMG + c * 8;
                v = *(const uint4*)src;
            }
            *(uint4*)(smem + 32768 + d * 128 + ((c ^ swz8(d)) * 16)) = v;
        }
    } else {
        #pragma unroll
        for (int t = 0; t < 4; ++t)
            *(uint4*)(smem + 32768 + (tid + t * 256) * 16) = make_uint4(0, 0, 0, 0);
        __syncthreads();
        for (int id = tid; id < 896; id += 256) {   // 56 j-rows x 16 d-chunks
            int j = id >> 4, cd = id & 15;
            int d0 = cd * 8;
            const u16* src = qk + ((long)b * HW + (long)j * IMG + rc) * ldqk + 1024 + n * 128 + d0;
            u16 vals[8];
            *(uint4*)vals = *(const uint4*)src;
            #pragma unroll
            for (int jj = 0; jj < 8; ++jj) {
                int d = d0 + jj;
                *(u16*)(smem + 32768 + d * 128 + (((j >> 3) ^ swz8(d)) * 16) + (j & 7) * 2) = vals[jj];
            }
        }
    }
    __syncthreads();

    const int l15 = lane & 15, lg = lane >> 4;
    const int istrip = wid * 16;

    // ---- S = Q^T K  (each wave: 16-row strip x 64 cols)
    bf16x8 aq[4];
    #pragma unroll
    for (int ks = 0; ks < 4; ++ks) {
        int row = istrip + l15;
        int ch = ks * 4 + lg;
        aq[ks] = *(const bf16x8*)(smem + row * 256 + ((ch ^ swz8(row)) * 16));
    }
    f32x4 sacc[4] = {};
    #pragma unroll
    for (int ct = 0; ct < 4; ++ct) {
        #pragma unroll
        for (int ks = 0; ks < 4; ++ks) {
            int j = ct * 16 + l15;
            int ch = ks * 4 + lg;
            bf16x8 kb = *(const bf16x8*)(smem + 16384 + j * 256 + ((ch ^ swz8(j)) * 16));
            sacc[ct] = mfma16(aq[ks], kb, sacc[ct]);
        }
    }

    // ---- softmax (wave-parallel, rows live on 16-lane groups)
    const float qscale = 0.08838834764831845f;   // 128^-0.5
    float pv[4][4];
    #pragma unroll
    for (int ct = 0; ct < 4; ++ct)
        #pragma unroll
        for (int r = 0; r < 4; ++r) {
            int i = istrip + lg * 4 + r;
            int j = ct * 16 + l15;
            float x = sacc[ct][r] * qscale;
            if (j < IMG) x += *(const float*)(smem + 57344 + (i - j + 55) * 4);
            else x = -1e30f;
            pv[ct][r] = x;
        }
    #pragma unroll
    for (int r = 0; r < 4; ++r) {
        float mx = fmaxf(fmaxf(pv[0][r], pv[1][r]), fmaxf(pv[2][r], pv[3][r]));
        mx = fmaxf(mx, __shfl_xor(mx, 1));
        mx = fmaxf(mx, __shfl_xor(mx, 2));
        mx = fmaxf(mx, __shfl_xor(mx, 4));
        mx = fmaxf(mx, __shfl_xor(mx, 8));
        float s0 = 0.f;
        #pragma unroll
        for (int ct = 0; ct < 4; ++ct) { pv[ct][r] = expf(pv[ct][r] - mx); s0 += pv[ct][r]; }
        s0 += __shfl_xor(s0, 1); s0 += __shfl_xor(s0, 2);
        s0 += __shfl_xor(s0, 4); s0 += __shfl_xor(s0, 8);
        float inv = 1.0f / s0;
        int i = istrip + lg * 4 + r;
        #pragma unroll
        for (int ct = 0; ct < 4; ++ct) {
            int j = ct * 16 + l15;
            *(u16*)(smem + 49152 + i * 128 + (((j >> 3) ^ swz8(i)) * 16) + (j & 7) * 2) = f2bf(pv[ct][r] * inv);
        }
    }
    __syncthreads();

    // ---- O = P V^T  (16-row strip x 128 d)
    bf16x8 pa[2];
    #pragma unroll
    for (int ks = 0; ks < 2; ++ks) {
        int row = istrip + l15;
        int ch = ks * 4 + lg;
        pa[ks] = *(const bf16x8*)(smem + 49152 + row * 128 + ((ch ^ swz8(row)) * 16));
    }
    f32x4 oacc[8] = {};
    #pragma unroll
    for (int dt = 0; dt < 8; ++dt) {
        #pragma unroll
        for (int ks = 0; ks < 2; ++ks) {
            int d = dt * 16 + l15;
            int ch = ks * 4 + lg;
            bf16x8 vb = *(const bf16x8*)(smem + 32768 + d * 128 + ((ch ^ swz8(d)) * 16));
            oacc[dt] = mfma16(pa[ks], vb, oacc[dt]);
        }
    }

    // ---- store with torch raw-reshape scramble
    #pragma unroll
    for (int dt = 0; dt < 8; ++dt) {
        #pragma unroll
        for (int r = 0; r < 4; ++r) {
            int i = istrip + lg * 4 + r;
            if (i >= IMG) continue;
            int d = dt * 16 + l15;
            int cch = (i & 3) * 128 + d;
            int im = n * 14 + (i >> 2);
            long addr;
            if (branch == 0) addr = ((long)b * 512 + cch) * HW + (long)rc * IMG + im;
            else             addr = ((long)b * 512 + cch) * HW + (long)im * IMG + rc;
            S[addr] = f2bf(oacc[dt][r]);
        }
    }
}

// ---------------------------------------------------------------------------
extern "C" void kernel_launch(void* const* d_in, const int* in_sizes, int n_in,
                              void* d_out, int out_size, void* d_ws, size_t ws_size,
                              hipStream_t stream)
{
    const float* x     = (const float*)d_in[0];
    const float* xq_w  = (const float*)d_in[1];
    const float* xq_b  = (const float*)d_in[2];
    const float* xk_w  = (const float*)d_in[3];
    const float* xk_b  = (const float*)d_in[4];
    const float* xv_w  = (const float*)d_in[5];
    const float* xv_b  = (const float*)d_in[6];
    const float* xp_w  = (const float*)d_in[7];
    const float* xp_b  = (const float*)d_in[8];
    const float* rel_x = (const float*)d_in[9];
    const float* yq_w  = (const float*)d_in[10];
    const float* yq_b  = (const float*)d_in[11];
    const float* yk_w  = (const float*)d_in[12];
    const float* yk_b  = (const float*)d_in[13];
    const float* yv_w  = (const float*)d_in[14];
    const float* yv_b  = (const float*)d_in[15];
    const float* yp_w  = (const float*)d_in[16];
    const float* yp_b  = (const float*)d_in[17];
    const float* rel_y = (const float*)d_in[18];
    const float* cp_w  = (const float*)d_in[19];
    const float* cp_b  = (const float*)d_in[20];
    const float* m1_w  = (const float*)d_in[21];
    const float* m1_b  = (const float*)d_in[22];
    const float* m2_w  = (const float*)d_in[23];
    const float* m2_b  = (const float*)d_in[24];
    const float* ls1   = (const float*)d_in[25];
    const float* ls2   = (const float*)d_in[26];

    if (ws_size < 128450560) return;  // need ~122.5 MB scratch

    char* ws = (char*)d_ws;
    u16* QKx  = (u16*)(ws + 0);          // [8][3136][1024] p-major Q|K (branch X)
    u16* Vx   = (u16*)(ws + 51380224);   // [8][512][3136]  m-major V   (branch X)
    u16* QKVy = (u16*)(ws + 0);          // [8][3136][1536] p-major QKV (branch Y), reuses region 0
    u16* Sb   = (u16*)(ws + 77070336);   // [8][512][3136]  scrambled attn out (X then Y)
    u16* AXY  = (u16*)(ws + 102760448);  // [8][256][3136]  concat(ax, ay)
    u16* NET  = (u16*)(ws + 115605504);  // [8][256][3136]
    u16* Hb   = (u16*)(ws + 0);          // [8][512][3136]  MLP hidden, reuses region 0

    dim3 blk(256, 1, 1);

    // 1) Q,K projections branch X (swapped -> p-major bf16)
    gemm128<<<dim3(25, 8, 8), blk, 0, stream>>>(xq_w, xk_w, nullptr, xq_b, xk_b, nullptr,
        x, 256, 0, 128, 1, QKx, 1024, 0, 1, 0, nullptr, nullptr, 0, 0, 0);
    // 2) V projection branch X (normal -> m-major bf16)
    gemm128<<<dim3(25, 4, 8), blk, 0, stream>>>(xv_w, nullptr, nullptr, xv_b, nullptr, nullptr,
        x, 256, 0, 128, 1, Vx, 512, 0, 0, 0, nullptr, nullptr, 0, 0, 0);
    // 3) attention branch X
    attn_kernel<<<dim3(56, 4, 8), blk, 0, stream>>>(QKx, 1024, Vx, rel_x, Sb, 0);
    // 4) out-projection X (+x residual, f32) -> AXY[0:128]
    gemm128<<<dim3(25, 1, 8), blk, 0, stream>>>(xp_w, nullptr, nullptr, xp_b, nullptr, nullptr,
        Sb, 512, 0, 512, 0, AXY, 256, 0, 0, 0, nullptr, x, 0, 1, 0);
    // 5) QKV projections branch Y (swapped -> p-major bf16)
    gemm128<<<dim3(25, 12, 8), blk, 0, stream>>>(yq_w, yk_w, yv_w, yq_b, yk_b, yv_b,
        x, 256, 128, 128, 1, QKVy, 1536, 0, 1, 0, nullptr, nullptr, 0, 0, 0);
    // 6) attention branch Y
    attn_kernel<<<dim3(56, 4, 8), blk, 0, stream>>>(QKVy, 1536, nullptr, rel_y, Sb, 1);
    // 7) out-projection Y (+x[:,128:] residual, f32) -> AXY[128:256]
    gemm128<<<dim3(25, 1, 8), blk, 0, stream>>>(yp_w, nullptr, nullptr, yp_b, nullptr, nullptr,
        Sb, 512, 0, 512, 0, AXY, 256, 128, 0, 0, nullptr, x, 128, 1, 0);
    // 8) cp conv, *ls1 + x residual (f32) -> NET
    gemm128<<<dim3(25, 2, 8), blk, 0, stream>>>(cp_w, nullptr, nullptr, cp_b, nullptr, nullptr,
        AXY, 256, 0, 256, 0, NET, 256, 0, 0, 0, ls1, x, 0, 1, 0);
    // 9) m1 + exact GELU -> Hb
    gemm128<<<dim3(25, 4, 8), blk, 0, stream>>>(m1_w, nullptr, nullptr, m1_b, nullptr, nullptr,
        NET, 256, 0, 256, 0, Hb, 512, 0, 0, 0, nullptr, nullptr, 0, 0, 1);
    // 10) m2, *ls2 + NET residual (bf16) -> out (f32)
    gemm128<<<dim3(25, 2, 8), blk, 0, stream>>>(m2_w, nullptr, nullptr, m2_b, nullptr, nullptr,
        Hb, 512, 0, 512, 0, d_out, 256, 0, 0, 1, ls2, NET, 0, 0, 0);
}

// Round 3
// 490.082 us; speedup vs baseline: 1.4841x; 1.4841x over previous
//
#include <hip/hip_runtime.h>

using u16 = unsigned short;
using u32 = unsigned int;

typedef short bf16x8 __attribute__((ext_vector_type(8)));
typedef float f32x4 __attribute__((ext_vector_type(4)));

#define HW 3136
#define IMG 56

__device__ __forceinline__ float bf2f(u16 v) {
    union { u32 u; float f; } c; c.u = ((u32)v) << 16; return c.f;
}
__device__ __forceinline__ u16 f2bf(float f) {
    union { float f; u32 u; } c; c.f = f;
    return (u16)((c.u + 0x7fffu + ((c.u >> 16) & 1u)) >> 16);
}
__device__ __forceinline__ int swz8(int r) { return (r ^ (r >> 3)) & 7; }

__device__ __forceinline__ f32x4 mfma16(bf16x8 a, bf16x8 b, f32x4 c) {
    return __builtin_amdgcn_mfma_f32_16x16x32_bf16(a, b, c, 0, 0, 0);
}

// ---------------------------------------------------------------------------
// transpose_x: x [b][256][HW] f32  ->  Xt [b][HW][256] bf16
// tile 64c x 64p per block, LDS chunk-XOR-swizzled to keep writes ~conflict-free
// ---------------------------------------------------------------------------
__global__ __launch_bounds__(256) void transpose_x(
    const float* __restrict__ x, u16* __restrict__ Xt)
{
    __shared__ u16 lds[64][80];   // 80: pad so 16B rows stay aligned
    const int t = threadIdx.x;
    const int Pb = blockIdx.x * 64;   // 49 tiles (49*64 = 3136 exact)
    const int Cb = blockIdx.y * 64;   // 4 tiles
    const int b  = blockIdx.z;

    #pragma unroll
    for (int q = 0; q < 4; ++q) {
        int id = t + q * 256;
        int c = id >> 4, pf = (id & 15) * 4;
        float4 v = *(const float4*)(x + ((long)(b * 256 + Cb + c)) * HW + Pb + pf);
        u16 vv[4] = { f2bf(v.x), f2bf(v.y), f2bf(v.z), f2bf(v.w) };
        #pragma unroll
        for (int j = 0; j < 4; ++j) {
            int p = pf + j;
            int cc = (((c >> 3) ^ ((p >> 2) & 7)) << 3) + (c & 7);
            lds[p][cc] = vv[j];
        }
    }
    __syncthreads();
    int p = t >> 2, cf = (t & 3) * 16;
    u16* dst = Xt + ((long)b * HW + Pb + p) * 256 + Cb + cf;
    int cc0 = ((cf >> 3) + 0) ^ ((p >> 2) & 7);
    int cc1 = ((cf >> 3) + 1) ^ ((p >> 2) & 7);
    *(uint4*)(dst + 0) = *(uint4*)&lds[p][cc0 * 8];
    *(uint4*)(dst + 8) = *(uint4*)&lds[p][cc1 * 8];
}

// ---------------------------------------------------------------------------
// pgemm: p-major GEMM for 1x1 convs.
//   out[p][outoff+m] = sum_k W[m][k] * act[p][choff+k]   (+bias, gelu, scale, res)
// act p-major bf16 [b*HW+p][actLd]; W f32 [M][K] (up to 3 stacked 512-row
// tensors for QKV); out p-major bf16 (or f32). res = Xt p-major bf16 [.][256].
// XCD-chunked block swizzle for L2 locality of shared act tiles.
// ---------------------------------------------------------------------------
__global__ __launch_bounds__(256) void pgemm(
    const float* __restrict__ w0, const float* __restrict__ w1, const float* __restrict__ w2,
    const float* __restrict__ bb0, const float* __restrict__ bb1, const float* __restrict__ bb2,
    const u16* __restrict__ act, int actLd, int choff, int K,
    void* __restrict__ out, int outLd, int outoff, int outF32,
    const float* __restrict__ scale, const u16* __restrict__ res, int resoff,
    int gelu)
{
    __shared__ __align__(16) char smem[32768];   // W tile 16K | act tile 16K
    const int tid = threadIdx.x;
    const int lane = tid & 63, wid = tid >> 6;
    const int l15 = lane & 15, lg = lane >> 4;

    // XCD-chunked swizzle: consecutive vid share a P-tile -> same XCD L2
    const int gy = gridDim.y;
    const int nwg = gridDim.x * gy * 8;
    int bid = blockIdx.x + gridDim.x * (blockIdx.y + gy * blockIdx.z);
    int vid = (bid & 7) * (nwg >> 3) + (bid >> 3);
    int bx = vid / (gy * 8);
    int rem = vid - bx * gy * 8;
    int by = rem >> 3;
    int bz = rem & 7;

    const int Pbase = bx * 128;
    const int Mbase = by * 128;
    const int sel = Mbase >> 9;
    const float* wsel = (sel == 0) ? w0 : ((sel == 1) ? w1 : w2);
    const float* bsel = (sel == 0) ? bb0 : ((sel == 1) ? bb1 : bb2);
    const int wrow0 = Mbase - sel * 512;

    f32x4 acc[4][4] = {};

    for (int ko = 0; ko < K; ko += 64) {
        // ---- stage W tile [128m][64k] f32->bf16, chunk-swizzled
        #pragma unroll
        for (int t = 0; t < 4; ++t) {
            int id = tid + t * 256;
            int row = id >> 3, c = id & 7;
            const float* src = wsel + (long)(wrow0 + row) * K + ko + c * 8;
            float4 f0 = *(const float4*)src;
            float4 f1 = *(const float4*)(src + 4);
            u16 tmp[8] = { f2bf(f0.x), f2bf(f0.y), f2bf(f0.z), f2bf(f0.w),
                           f2bf(f1.x), f2bf(f1.y), f2bf(f1.z), f2bf(f1.w) };
            *(uint4*)(smem + row * 128 + ((c ^ swz8(row)) * 16)) = *(uint4*)tmp;
        }
        // ---- stage act tile [128p][64k] direct vectorized (already p-major)
        #pragma unroll
        for (int t = 0; t < 4; ++t) {
            int id = tid + t * 256;
            int prow = id >> 3, c = id & 7;
            int pg = Pbase + prow;
            uint4 v = make_uint4(0, 0, 0, 0);
            if (pg < HW)
                v = *(const uint4*)(act + ((long)bz * HW + pg) * actLd + choff + ko + c * 8);
            *(uint4*)(smem + 16384 + prow * 128 + ((c ^ swz8(prow)) * 16)) = v;
        }
        __syncthreads();

        #pragma unroll
        for (int ks = 0; ks < 2; ++ks) {
            const int ch = ks * 4 + lg;
            bf16x8 af[4], bfr[4];
            #pragma unroll
            for (int rt = 0; rt < 4; ++rt) {
                int p = (wid >> 1) * 64 + rt * 16 + l15;
                af[rt] = *(const bf16x8*)(smem + 16384 + p * 128 + ((ch ^ swz8(p)) * 16));
            }
            #pragma unroll
            for (int ct = 0; ct < 4; ++ct) {
                int m = (wid & 1) * 64 + ct * 16 + l15;
                bfr[ct] = *(const bf16x8*)(smem + m * 128 + ((ch ^ swz8(m)) * 16));
            }
            #pragma unroll
            for (int rt = 0; rt < 4; ++rt)
                #pragma unroll
                for (int ct = 0; ct < 4; ++ct)
                    acc[rt][ct] = mfma16(af[rt], bfr[ct], acc[rt][ct]);
        }
        __syncthreads();
    }

    // ---- epilogue: p rows via (rt, lg*4+r), channels via (ct, l15)
    #pragma unroll
    for (int rt = 0; rt < 4; ++rt) {
      #pragma unroll
      for (int ct = 0; ct < 4; ++ct) {
        #pragma unroll
        for (int r = 0; r < 4; ++r) {
            int p = Pbase + (wid >> 1) * 64 + rt * 16 + lg * 4 + r;
            if (p >= HW) continue;
            int mg = Mbase + (wid & 1) * 64 + ct * 16 + l15;
            float v = acc[rt][ct][r] + bsel[mg - sel * 512];
            if (gelu)  v = v * 0.5f * (1.0f + erff(v * 0.70710678118f));
            if (scale) v *= scale[outoff + mg];
            if (res)   v += bf2f(res[((long)bz * HW + p) * 256 + resoff + mg]);
            long oaddr = ((long)bz * HW + p) * outLd + outoff + mg;
            if (outF32) ((float*)out)[oaddr] = v;
            else        ((u16*)out)[oaddr]   = f2bf(v);
        }
      }
    }
}

// ---------------------------------------------------------------------------
// Axial attention, one block per (b, row-or-col, head). 4 waves.
// QKV p-major bf16 [b*HW+p][1536] (Q 0..511, K 512..1023, V 1024..1535).
// Writes p-major scrambled Sb [b*HW+p][512]: w' = n*14 + i/4, c = (i%4)*128+d.
// ---------------------------------------------------------------------------
__global__ __launch_bounds__(256) void attn_kernel(
    const u16* __restrict__ qkv,
    const float* __restrict__ rel,
    u16* __restrict__ S, int branch)
{
    __shared__ __align__(16) char smem[57856];
    // QT:[0,16K) KT:[16K,32K) V:[32K,48K) P:[49152,57344) RELf32:[57344,57856)
    const int tid = threadIdx.x;
    const int lane = tid & 63, wid = tid >> 6;
    const int rc = blockIdx.x;   // image row (branch 0) / image col (branch 1)
    const int n  = blockIdx.y;
    const int b  = blockIdx.z;

    if (tid < 128) {
        float v = (tid < 112) ? rel[n * HW + tid] : 0.0f;
        *(float*)(smem + 57344 + tid * 4) = v;
    }
    // zero V region (cols >= 56 must be 0 to avoid NaN*0 in PV)
    #pragma unroll
    for (int t = 0; t < 4; ++t)
        *(uint4*)(smem + 32768 + (tid + t * 256) * 16) = make_uint4(0, 0, 0, 0);
    __syncthreads();

    // ---- stage Qt/Kt [64][128] seq-major (zero-padded rows >= 56)
    #pragma unroll
    for (int t = 0; t < 4; ++t) {
        int id = tid + t * 256;
        int i = id >> 4, c = id & 15;
        uint4 v  = make_uint4(0, 0, 0, 0);
        uint4 v2 = make_uint4(0, 0, 0, 0);
        if (i < IMG) {
            long p = (branch == 0) ? ((long)rc * IMG + i) : ((long)i * IMG + rc);
            const u16* src = qkv + ((long)b * HW + p) * 1536 + n * 128 + c * 8;
            v  = *(const uint4*)src;
            v2 = *(const uint4*)(src + 512);
        }
        int off = i * 256 + ((c ^ swz8(i)) * 16);
        *(uint4*)(smem + off) = v;
        *(uint4*)(smem + 16384 + off) = v2;
    }
    // ---- stage V [128d][64j] via small scatter transpose
    for (int id = tid; id < 896; id += 256) {   // 56 j x 16 d-chunks
        int j = id >> 4, d0 = (id & 15) * 8;
        long p = (branch == 0) ? ((long)rc * IMG + j) : ((long)j * IMG + rc);
        const u16* src = qkv + ((long)b * HW + p) * 1536 + 1024 + n * 128 + d0;
        u16 vals[8];
        *(uint4*)vals = *(const uint4*)src;
        #pragma unroll
        for (int jj = 0; jj < 8; ++jj) {
            int d = d0 + jj;
            *(u16*)(smem + 32768 + d * 128 + (((j >> 3) ^ swz8(d)) * 16) + (j & 7) * 2) = vals[jj];
        }
    }
    __syncthreads();

    const int l15 = lane & 15, lg = lane >> 4;
    const int istrip = wid * 16;

    // ---- S = Q^T K  (each wave: 16-row strip x 64 cols)
    bf16x8 aq[4];
    #pragma unroll
    for (int ks = 0; ks < 4; ++ks) {
        int row = istrip + l15;
        int ch = ks * 4 + lg;
        aq[ks] = *(const bf16x8*)(smem + row * 256 + ((ch ^ swz8(row)) * 16));
    }
    f32x4 sacc[4] = {};
    #pragma unroll
    for (int ct = 0; ct < 4; ++ct) {
        #pragma unroll
        for (int ks = 0; ks < 4; ++ks) {
            int j = ct * 16 + l15;
            int ch = ks * 4 + lg;
            bf16x8 kb = *(const bf16x8*)(smem + 16384 + j * 256 + ((ch ^ swz8(j)) * 16));
            sacc[ct] = mfma16(aq[ks], kb, sacc[ct]);
        }
    }

    // ---- softmax (wave-parallel, rows live on 16-lane groups)
    const float qscale = 0.08838834764831845f;   // 128^-0.5
    float pv[4][4];
    #pragma unroll
    for (int ct = 0; ct < 4; ++ct)
        #pragma unroll
        for (int r = 0; r < 4; ++r) {
            int i = istrip + lg * 4 + r;
            int j = ct * 16 + l15;
            float x = sacc[ct][r] * qscale;
            if (j < IMG) x += *(const float*)(smem + 57344 + (i - j + 55) * 4);
            else x = -1e30f;
            pv[ct][r] = x;
        }
    #pragma unroll
    for (int r = 0; r < 4; ++r) {
        float mx = fmaxf(fmaxf(pv[0][r], pv[1][r]), fmaxf(pv[2][r], pv[3][r]));
        mx = fmaxf(mx, __shfl_xor(mx, 1));
        mx = fmaxf(mx, __shfl_xor(mx, 2));
        mx = fmaxf(mx, __shfl_xor(mx, 4));
        mx = fmaxf(mx, __shfl_xor(mx, 8));
        float s0 = 0.f;
        #pragma unroll
        for (int ct = 0; ct < 4; ++ct) { pv[ct][r] = expf(pv[ct][r] - mx); s0 += pv[ct][r]; }
        s0 += __shfl_xor(s0, 1); s0 += __shfl_xor(s0, 2);
        s0 += __shfl_xor(s0, 4); s0 += __shfl_xor(s0, 8);
        float inv = 1.0f / s0;
        int i = istrip + lg * 4 + r;
        #pragma unroll
        for (int ct = 0; ct < 4; ++ct) {
            int j = ct * 16 + l15;
            *(u16*)(smem + 49152 + i * 128 + (((j >> 3) ^ swz8(i)) * 16) + (j & 7) * 2) = f2bf(pv[ct][r] * inv);
        }
    }
    __syncthreads();

    // ---- O = P V^T  (16-row strip x 128 d)
    bf16x8 pa[2];
    #pragma unroll
    for (int ks = 0; ks < 2; ++ks) {
        int row = istrip + l15;
        int ch = ks * 4 + lg;
        pa[ks] = *(const bf16x8*)(smem + 49152 + row * 128 + ((ch ^ swz8(row)) * 16));
    }
    f32x4 oacc[8] = {};
    #pragma unroll
    for (int dt = 0; dt < 8; ++dt) {
        #pragma unroll
        for (int ks = 0; ks < 2; ++ks) {
            int d = dt * 16 + l15;
            int ch = ks * 4 + lg;
            bf16x8 vb = *(const bf16x8*)(smem + 32768 + d * 128 + ((ch ^ swz8(d)) * 16));
            oacc[dt] = mfma16(pa[ks], vb, oacc[dt]);
        }
    }

    // ---- store p-major with torch raw-reshape scramble (32B chunks/lane-group)
    #pragma unroll
    for (int dt = 0; dt < 8; ++dt) {
        #pragma unroll
        for (int r = 0; r < 4; ++r) {
            int i = istrip + lg * 4 + r;
            if (i >= IMG) continue;
            int d = dt * 16 + l15;
            int cch = (i & 3) * 128 + d;
            int im = n * 14 + (i >> 2);
            long p = (branch == 0) ? ((long)rc * IMG + im) : ((long)im * IMG + rc);
            S[((long)b * HW + p) * 512 + cch] = f2bf(oacc[dt][r]);
        }
    }
}

// ---------------------------------------------------------------------------
// fuse_out: d_out[b][c][p] (f32, m-major) = OUTp[b][p][c] (f32) + NETp[b][p][c]
// tile 128p x 32c, LDS transpose.
// ---------------------------------------------------------------------------
__global__ __launch_bounds__(256) void fuse_out(
    const float* __restrict__ OUTp, const u16* __restrict__ NETp,
    float* __restrict__ y)
{
    __shared__ float lds[32][132];
    const int t = threadIdx.x;
    const int Pb = blockIdx.x * 128;
    const int Cb = blockIdx.y * 32;
    const int b  = blockIdx.z;

    #pragma unroll
    for (int q = 0; q < 4; ++q) {
        int id = t + q * 256;          // 128p x 8 c-chunks
        int p = id >> 3, cq = (id & 7) * 4;
        int pg = Pb + p;
        float4 v = make_float4(0.f, 0.f, 0.f, 0.f);
        if (pg < HW) {
            v = *(const float4*)(OUTp + ((long)b * HW + pg) * 256 + Cb + cq);
            ushort4 nv = *(const ushort4*)(NETp + ((long)b * HW + pg) * 256 + Cb + cq);
            v.x += bf2f(nv.x); v.y += bf2f(nv.y); v.z += bf2f(nv.z); v.w += bf2f(nv.w);
        }
        lds[cq + 0][p] = v.x; lds[cq + 1][p] = v.y;
        lds[cq + 2][p] = v.z; lds[cq + 3][p] = v.w;
    }
    __syncthreads();
    #pragma unroll
    for (int q = 0; q < 4; ++q) {
        int id = t + q * 256;          // 32c x 32 p-chunks
        int c = id >> 5, pq = (id & 31) * 4;
        int pg = Pb + pq;
        if (pg + 3 < HW) {
            float4 v = make_float4(lds[c][pq], lds[c][pq + 1], lds[c][pq + 2], lds[c][pq + 3]);
            *(float4*)(y + ((long)(b * 256 + Cb + c)) * HW + pg) = v;
        }
    }
}

// ---------------------------------------------------------------------------
extern "C" void kernel_launch(void* const* d_in, const int* in_sizes, int n_in,
                              void* d_out, int out_size, void* d_ws, size_t ws_size,
                              hipStream_t stream)
{
    const float* x     = (const float*)d_in[0];
    const float* xq_w  = (const float*)d_in[1];
    const float* xq_b  = (const float*)d_in[2];
    const float* xk_w  = (const float*)d_in[3];
    const float* xk_b  = (const float*)d_in[4];
    const float* xv_w  = (const float*)d_in[5];
    const float* xv_b  = (const float*)d_in[6];
    const float* xp_w  = (const float*)d_in[7];
    const float* xp_b  = (const float*)d_in[8];
    const float* rel_x = (const float*)d_in[9];
    const float* yq_w  = (const float*)d_in[10];
    const float* yq_b  = (const float*)d_in[11];
    const float* yk_w  = (const float*)d_in[12];
    const float* yk_b  = (const float*)d_in[13];
    const float* yv_w  = (const float*)d_in[14];
    const float* yv_b  = (const float*)d_in[15];
    const float* yp_w  = (const float*)d_in[16];
    const float* yp_b  = (const float*)d_in[17];
    const float* rel_y = (const float*)d_in[18];
    const float* cp_w  = (const float*)d_in[19];
    const float* cp_b  = (const float*)d_in[20];
    const float* m1_w  = (const float*)d_in[21];
    const float* m1_b  = (const float*)d_in[22];
    const float* m2_w  = (const float*)d_in[23];
    const float* m2_b  = (const float*)d_in[24];
    const float* ls1   = (const float*)d_in[25];
    const float* ls2   = (const float*)d_in[26];

    if (ws_size < 128450560) return;

    char* ws = (char*)d_ws;
    u16*   QKV  = (u16*)(ws + 0);            // [8][3136][1536] bf16 (77,070,336 B)
    u16*   Hb   = (u16*)(ws + 0);            // [8][3136][512]  bf16 (reuses dead QKV)
    float* OUTp = (float*)(ws + 25690112);   // [8][3136][256]  f32  (reuses dead QKV)
    u16*   Xt   = (u16*)(ws + 77070336);     // [8][3136][256]  bf16
    u16*   Sb   = (u16*)(ws + 89915392);     // [8][3136][512]  bf16
    u16*   NETp = (u16*)(ws + 89915392);     // [8][3136][256]  bf16 (reuses dead Sb)
    u16*   AXY  = (u16*)(ws + 115605504);    // [8][3136][256]  bf16

    dim3 blk(256, 1, 1);

    // 0) x -> Xt (p-major bf16)
    transpose_x<<<dim3(49, 4, 8), blk, 0, stream>>>(x, Xt);
    // 1) QKV projection branch X (x channels 0..127)
    pgemm<<<dim3(25, 12, 8), blk, 0, stream>>>(xq_w, xk_w, xv_w, xq_b, xk_b, xv_b,
        Xt, 256, 0, 128, QKV, 1536, 0, 0, nullptr, nullptr, 0, 0);
    // 2) attention branch X -> Sb
    attn_kernel<<<dim3(56, 4, 8), blk, 0, stream>>>(QKV, rel_x, Sb, 0);
    // 3) out-projection X (+Xt[:,0:128] residual) -> AXY[:, 0:128]
    pgemm<<<dim3(25, 1, 8), blk, 0, stream>>>(xp_w, nullptr, nullptr, xp_b, nullptr, nullptr,
        Sb, 512, 0, 512, AXY, 256, 0, 0, nullptr, Xt, 0, 0);
    // 4) QKV projection branch Y (x channels 128..255)
    pgemm<<<dim3(25, 12, 8), blk, 0, stream>>>(yq_w, yk_w, yv_w, yq_b, yk_b, yv_b,
        Xt, 256, 128, 128, QKV, 1536, 0, 0, nullptr, nullptr, 0, 0);
    // 5) attention branch Y -> Sb
    attn_kernel<<<dim3(56, 4, 8), blk, 0, stream>>>(QKV, rel_y, Sb, 1);
    // 6) out-projection Y (+Xt[:,128:256] residual) -> AXY[:, 128:256]
    pgemm<<<dim3(25, 1, 8), blk, 0, stream>>>(yp_w, nullptr, nullptr, yp_b, nullptr, nullptr,
        Sb, 512, 0, 512, AXY, 256, 128, 0, nullptr, Xt, 128, 0);
    // 7) cp conv, *ls1 + x residual -> NETp
    pgemm<<<dim3(25, 2, 8), blk, 0, stream>>>(cp_w, nullptr, nullptr, cp_b, nullptr, nullptr,
        AXY, 256, 0, 256, NETp, 256, 0, 0, ls1, Xt, 0, 0);
    // 8) m1 + exact GELU -> Hb
    pgemm<<<dim3(25, 4, 8), blk, 0, stream>>>(m1_w, nullptr, nullptr, m1_b, nullptr, nullptr,
        NETp, 256, 0, 256, Hb, 512, 0, 0, nullptr, nullptr, 0, 1);
    // 9) m2, *ls2 -> OUTp (f32 p-major)
    pgemm<<<dim3(25, 2, 8), blk, 0, stream>>>(m2_w, nullptr, nullptr, m2_b, nullptr, nullptr,
        Hb, 512, 0, 512, OUTp, 256, 0, 1, ls2, nullptr, 0, 0);
    // 10) d_out = transpose(OUTp) + NETp  (m-major f32)
    fuse_out<<<dim3(25, 8, 8), blk, 0, stream>>>(OUTp, NETp, (float*)d_out);
}

// Round 4
// 360.023 us; speedup vs baseline: 2.0202x; 1.3613x over previous
//
#include <hip/hip_runtime.h>

using u16 = unsigned short;
using u32 = unsigned int;

typedef short bf16x8 __attribute__((ext_vector_type(8)));
typedef float f32x4 __attribute__((ext_vector_type(4)));

#define HW 3136
#define IMG 56

__device__ __forceinline__ float bf2f(u16 v) {
    union { u32 u; float f; } c; c.u = ((u32)v) << 16; return c.f;
}
__device__ __forceinline__ u16 f2bf(float f) {
    union { float f; u32 u; } c; c.f = f;
    return (u16)((c.u + 0x7fffu + ((c.u >> 16) & 1u)) >> 16);
}
// pack 2 f32 -> 2 bf16 in one u32 (RNE, hardware cvt)
__device__ __forceinline__ u32 pk2bf(float a, float b) {
    u32 r;
    asm("v_cvt_pk_bf16_f32 %0, %1, %2" : "=v"(r) : "v"(a), "v"(b));
    return r;
}
__device__ __forceinline__ int swz8(int r) { return (r ^ (r >> 3)) & 7; }

__device__ __forceinline__ f32x4 mfma16(bf16x8 a, bf16x8 b, f32x4 c) {
    return __builtin_amdgcn_mfma_f32_16x16x32_bf16(a, b, c, 0, 0, 0);
}

// ---------------------------------------------------------------------------
// transpose_x: x [b][256][HW] f32  ->  Xt [b][HW][256] bf16
// ---------------------------------------------------------------------------
__global__ __launch_bounds__(256) void transpose_x(
    const float* __restrict__ x, u16* __restrict__ Xt)
{
    __shared__ u16 lds[64][80];
    const int t = threadIdx.x;
    const int Pb = blockIdx.x * 64;
    const int Cb = blockIdx.y * 64;
    const int b  = blockIdx.z;

    #pragma unroll
    for (int q = 0; q < 4; ++q) {
        int id = t + q * 256;
        int c = id >> 4, pf = (id & 15) * 4;
        float4 v = *(const float4*)(x + ((long)(b * 256 + Cb + c)) * HW + Pb + pf);
        u16 vv[4] = { f2bf(v.x), f2bf(v.y), f2bf(v.z), f2bf(v.w) };
        #pragma unroll
        for (int j = 0; j < 4; ++j) {
            int p = pf + j;
            int cc = (((c >> 3) ^ ((p >> 2) & 7)) << 3) + (c & 7);
            lds[p][cc] = vv[j];
        }
    }
    __syncthreads();
    int p = t >> 2, cf = (t & 3) * 16;
    u16* dst = Xt + ((long)b * HW + Pb + p) * 256 + Cb + cf;
    int cc0 = ((cf >> 3) + 0) ^ ((p >> 2) & 7);
    int cc1 = ((cf >> 3) + 1) ^ ((p >> 2) & 7);
    *(uint4*)(dst + 0) = *(uint4*)&lds[p][cc0 * 8];
    *(uint4*)(dst + 8) = *(uint4*)&lds[p][cc1 * 8];
}

// ---------------------------------------------------------------------------
// pgemm: p-major GEMM for 1x1 convs.
//   out[p][outoff+m] = sum_k W[m][k] * act[p][choff+k]   (+bias, gelu, scale, res)
// MFMA args ordered (W, act) so D rows = m, cols = p: each thread holds 4
// CONSECUTIVE m at fixed p -> packed 8B stores into p-major output.
// ---------------------------------------------------------------------------
__global__ __launch_bounds__(256) void pgemm(
    const float* __restrict__ w0, const float* __restrict__ w1, const float* __restrict__ w2,
    const float* __restrict__ bb0, const float* __restrict__ bb1, const float* __restrict__ bb2,
    const u16* __restrict__ act, int actLd, int choff, int K,
    void* __restrict__ out, int outLd, int outoff, int outF32,
    const float* __restrict__ scale, const u16* __restrict__ res, int resoff,
    int gelu)
{
    __shared__ __align__(16) char smem[32768];   // W tile 16K | act tile 16K
    const int tid = threadIdx.x;
    const int lane = tid & 63, wid = tid >> 6;
    const int l15 = lane & 15, lg = lane >> 4;

    // XCD-chunked swizzle
    const int gy = gridDim.y;
    const int nwg = gridDim.x * gy * 8;
    int bid = blockIdx.x + gridDim.x * (blockIdx.y + gy * blockIdx.z);
    int vid = (bid & 7) * (nwg >> 3) + (bid >> 3);
    int bx = vid / (gy * 8);
    int rem = vid - bx * gy * 8;
    int by = rem >> 3;
    int bz = rem & 7;

    const int Pbase = bx * 128;
    const int Mbase = by * 128;
    const int sel = Mbase >> 9;
    const float* wsel = (sel == 0) ? w0 : ((sel == 1) ? w1 : w2);
    const float* bsel = (sel == 0) ? bb0 : ((sel == 1) ? bb1 : bb2);
    const int wrow0 = Mbase - sel * 512;

    f32x4 acc[4][4] = {};   // acc[p-tile rt][m-tile ct][m-reg]

    for (int ko = 0; ko < K; ko += 64) {
        // ---- stage W tile [128m][64k] f32->bf16 (cvt_pk), chunk-swizzled
        #pragma unroll
        for (int t = 0; t < 4; ++t) {
            int id = tid + t * 256;
            int row = id >> 3, c = id & 7;
            const float* src = wsel + (long)(wrow0 + row) * K + ko + c * 8;
            float4 f0 = *(const float4*)src;
            float4 f1 = *(const float4*)(src + 4);
            u32 tmp[4] = { pk2bf(f0.x, f0.y), pk2bf(f0.z, f0.w),
                           pk2bf(f1.x, f1.y), pk2bf(f1.z, f1.w) };
            *(uint4*)(smem + row * 128 + ((c ^ swz8(row)) * 16)) = *(uint4*)tmp;
        }
        // ---- stage act tile [128p][64k] direct vectorized
        #pragma unroll
        for (int t = 0; t < 4; ++t) {
            int id = tid + t * 256;
            int prow = id >> 3, c = id & 7;
            int pg = Pbase + prow;
            uint4 v = make_uint4(0, 0, 0, 0);
            if (pg < HW)
                v = *(const uint4*)(act + ((long)bz * HW + pg) * actLd + choff + ko + c * 8);
            *(uint4*)(smem + 16384 + prow * 128 + ((c ^ swz8(prow)) * 16)) = v;
        }
        __syncthreads();

        #pragma unroll
        for (int ks = 0; ks < 2; ++ks) {
            const int ch = ks * 4 + lg;
            bf16x8 af[4], bfr[4];
            #pragma unroll
            for (int rt = 0; rt < 4; ++rt) {
                int p = (wid >> 1) * 64 + rt * 16 + l15;
                af[rt] = *(const bf16x8*)(smem + 16384 + p * 128 + ((ch ^ swz8(p)) * 16));
            }
            #pragma unroll
            for (int ct = 0; ct < 4; ++ct) {
                int m = (wid & 1) * 64 + ct * 16 + l15;
                bfr[ct] = *(const bf16x8*)(smem + m * 128 + ((ch ^ swz8(m)) * 16));
            }
            #pragma unroll
            for (int rt = 0; rt < 4; ++rt)
                #pragma unroll
                for (int ct = 0; ct < 4; ++ct)
                    acc[rt][ct] = mfma16(bfr[ct], af[rt], acc[rt][ct]);   // A=W, B=act
        }
        __syncthreads();
    }

    // ---- epilogue: thread holds 4 consecutive m (lg*4..+3) at fixed p (l15)
    #pragma unroll
    for (int rt = 0; rt < 4; ++rt) {
        int p = Pbase + (wid >> 1) * 64 + rt * 16 + l15;
        if (p >= HW) continue;
        long rowp = (long)bz * HW + p;
        #pragma unroll
        for (int ct = 0; ct < 4; ++ct) {
            int mloc = (wid & 1) * 64 + ct * 16 + lg * 4;   // local within 128-tile
            int mg = Mbase + mloc;                          // global m
            float4 bv = *(const float4*)(bsel + wrow0 + mloc);
            float v[4];
            #pragma unroll
            for (int j = 0; j < 4; ++j) {
                float tt = acc[rt][ct][j] + ((const float*)&bv)[j];
                if (gelu) tt = tt * 0.5f * (1.0f + erff(tt * 0.70710678118f));
                v[j] = tt;
            }
            if (scale) {
                float4 sv = *(const float4*)(scale + outoff + mg);
                v[0] *= sv.x; v[1] *= sv.y; v[2] *= sv.z; v[3] *= sv.w;
            }
            if (res) {
                ushort4 rv = *(const ushort4*)(res + rowp * 256 + resoff + mg);
                v[0] += bf2f(rv.x); v[1] += bf2f(rv.y);
                v[2] += bf2f(rv.z); v[3] += bf2f(rv.w);
            }
            long oaddr = rowp * outLd + outoff + mg;
            if (outF32) {
                *(float4*)((float*)out + oaddr) = make_float4(v[0], v[1], v[2], v[3]);
            } else {
                *(uint2*)((u16*)out + oaddr) = make_uint2(pk2bf(v[0], v[1]), pk2bf(v[2], v[3]));
            }
        }
    }
}

// ---------------------------------------------------------------------------
// Axial attention, one block per (b, row-or-col, head). 4 waves.
// PV uses swapped operands (A=V, B=P) so each thread holds 4 consecutive d
// at fixed i -> packed 8B stores of the scrambled p-major Sb.
// ---------------------------------------------------------------------------
__global__ __launch_bounds__(256) void attn_kernel(
    const u16* __restrict__ qkv,
    const float* __restrict__ rel,
    u16* __restrict__ S, int branch)
{
    __shared__ __align__(16) char smem[57856];
    // QT:[0,16K) KT:[16K,32K) V:[32K,48K) P:[49152,57344) RELf32:[57344,57856)
    const int tid = threadIdx.x;
    const int lane = tid & 63, wid = tid >> 6;
    const int rc = blockIdx.x;
    const int n  = blockIdx.y;
    const int b  = blockIdx.z;

    if (tid < 128) {
        float v = (tid < 112) ? rel[n * HW + tid] : 0.0f;
        *(float*)(smem + 57344 + tid * 4) = v;
    }
    #pragma unroll
    for (int t = 0; t < 4; ++t)
        *(uint4*)(smem + 32768 + (tid + t * 256) * 16) = make_uint4(0, 0, 0, 0);
    __syncthreads();

    // ---- stage Qt/Kt [64][128] seq-major
    #pragma unroll
    for (int t = 0; t < 4; ++t) {
        int id = tid + t * 256;
        int i = id >> 4, c = id & 15;
        uint4 v  = make_uint4(0, 0, 0, 0);
        uint4 v2 = make_uint4(0, 0, 0, 0);
        if (i < IMG) {
            long p = (branch == 0) ? ((long)rc * IMG + i) : ((long)i * IMG + rc);
            const u16* src = qkv + ((long)b * HW + p) * 1536 + n * 128 + c * 8;
            v  = *(const uint4*)src;
            v2 = *(const uint4*)(src + 512);
        }
        int off = i * 256 + ((c ^ swz8(i)) * 16);
        *(uint4*)(smem + off) = v;
        *(uint4*)(smem + 16384 + off) = v2;
    }
    // ---- stage V [128d][64j] via small scatter transpose
    for (int id = tid; id < 896; id += 256) {
        int j = id >> 4, d0 = (id & 15) * 8;
        long p = (branch == 0) ? ((long)rc * IMG + j) : ((long)j * IMG + rc);
        const u16* src = qkv + ((long)b * HW + p) * 1536 + 1024 + n * 128 + d0;
        u16 vals[8];
        *(uint4*)vals = *(const uint4*)src;
        #pragma unroll
        for (int jj = 0; jj < 8; ++jj) {
            int d = d0 + jj;
            *(u16*)(smem + 32768 + d * 128 + (((j >> 3) ^ swz8(d)) * 16) + (j & 7) * 2) = vals[jj];
        }
    }
    __syncthreads();

    const int l15 = lane & 15, lg = lane >> 4;
    const int istrip = wid * 16;

    // ---- S = Q^T K
    bf16x8 aq[4];
    #pragma unroll
    for (int ks = 0; ks < 4; ++ks) {
        int row = istrip + l15;
        int ch = ks * 4 + lg;
        aq[ks] = *(const bf16x8*)(smem + row * 256 + ((ch ^ swz8(row)) * 16));
    }
    f32x4 sacc[4] = {};
    #pragma unroll
    for (int ct = 0; ct < 4; ++ct) {
        #pragma unroll
        for (int ks = 0; ks < 4; ++ks) {
            int j = ct * 16 + l15;
            int ch = ks * 4 + lg;
            bf16x8 kb = *(const bf16x8*)(smem + 16384 + j * 256 + ((ch ^ swz8(j)) * 16));
            sacc[ct] = mfma16(aq[ks], kb, sacc[ct]);
        }
    }

    // ---- softmax
    const float qscale = 0.08838834764831845f;
    float pv[4][4];
    #pragma unroll
    for (int ct = 0; ct < 4; ++ct)
        #pragma unroll
        for (int r = 0; r < 4; ++r) {
            int i = istrip + lg * 4 + r;
            int j = ct * 16 + l15;
            float x = sacc[ct][r] * qscale;
            if (j < IMG) x += *(const float*)(smem + 57344 + (i - j + 55) * 4);
            else x = -1e30f;
            pv[ct][r] = x;
        }
    #pragma unroll
    for (int r = 0; r < 4; ++r) {
        float mx = fmaxf(fmaxf(pv[0][r], pv[1][r]), fmaxf(pv[2][r], pv[3][r]));
        mx = fmaxf(mx, __shfl_xor(mx, 1));
        mx = fmaxf(mx, __shfl_xor(mx, 2));
        mx = fmaxf(mx, __shfl_xor(mx, 4));
        mx = fmaxf(mx, __shfl_xor(mx, 8));
        float s0 = 0.f;
        #pragma unroll
        for (int ct = 0; ct < 4; ++ct) { pv[ct][r] = expf(pv[ct][r] - mx); s0 += pv[ct][r]; }
        s0 += __shfl_xor(s0, 1); s0 += __shfl_xor(s0, 2);
        s0 += __shfl_xor(s0, 4); s0 += __shfl_xor(s0, 8);
        float inv = 1.0f / s0;
        int i = istrip + lg * 4 + r;
        #pragma unroll
        for (int ct = 0; ct < 4; ++ct) {
            int j = ct * 16 + l15;
            *(u16*)(smem + 49152 + i * 128 + (((j >> 3) ^ swz8(i)) * 16) + (j & 7) * 2) = f2bf(pv[ct][r] * inv);
        }
    }
    __syncthreads();

    // ---- O = P V^T with A=V, B=P: D rows = d, cols = i
    bf16x8 pa[2];
    #pragma unroll
    for (int ks = 0; ks < 2; ++ks) {
        int row = istrip + l15;
        int ch = ks * 4 + lg;
        pa[ks] = *(const bf16x8*)(smem + 49152 + row * 128 + ((ch ^ swz8(row)) * 16));
    }
    f32x4 oacc[8] = {};
    #pragma unroll
    for (int dt = 0; dt < 8; ++dt) {
        #pragma unroll
        for (int ks = 0; ks < 2; ++ks) {
            int d = dt * 16 + l15;
            int ch = ks * 4 + lg;
            bf16x8 vb = *(const bf16x8*)(smem + 32768 + d * 128 + ((ch ^ swz8(d)) * 16));
            oacc[dt] = mfma16(vb, pa[ks], oacc[dt]);
        }
    }

    // ---- store p-major scrambled, packed 8B per (dt)
    const int i = istrip + l15;
    if (i < IMG) {
        int im = n * 14 + (i >> 2);
        long p = (branch == 0) ? ((long)rc * IMG + im) : ((long)im * IMG + rc);
        u16* dst = S + ((long)b * HW + p) * 512 + (i & 3) * 128;
        #pragma unroll
        for (int dt = 0; dt < 8; ++dt) {
            int d4 = dt * 16 + lg * 4;
            *(uint2*)(dst + d4) = make_uint2(pk2bf(oacc[dt][0], oacc[dt][1]),
                                             pk2bf(oacc[dt][2], oacc[dt][3]));
        }
    }
}

// ---------------------------------------------------------------------------
// fuse_out: d_out[b][c][p] (f32, m-major) = OUTp[b][p][c] + NETp[b][p][c]
// ---------------------------------------------------------------------------
__global__ __launch_bounds__(256) void fuse_out(
    const float* __restrict__ OUTp, const u16* __restrict__ NETp,
    float* __restrict__ y)
{
    __shared__ float lds[32][132];
    const int t = threadIdx.x;
    const int Pb = blockIdx.x * 128;
    const int Cb = blockIdx.y * 32;
    const int b  = blockIdx.z;

    #pragma unroll
    for (int q = 0; q < 4; ++q) {
        int id = t + q * 256;
        int p = id >> 3, cq = (id & 7) * 4;
        int pg = Pb + p;
        float4 v = make_float4(0.f, 0.f, 0.f, 0.f);
        if (pg < HW) {
            v = *(const float4*)(OUTp + ((long)b * HW + pg) * 256 + Cb + cq);
            ushort4 nv = *(const ushort4*)(NETp + ((long)b * HW + pg) * 256 + Cb + cq);
            v.x += bf2f(nv.x); v.y += bf2f(nv.y); v.z += bf2f(nv.z); v.w += bf2f(nv.w);
        }
        lds[cq + 0][p] = v.x; lds[cq + 1][p] = v.y;
        lds[cq + 2][p] = v.z; lds[cq + 3][p] = v.w;
    }
    __syncthreads();
    #pragma unroll
    for (int q = 0; q < 4; ++q) {
        int id = t + q * 256;
        int c = id >> 5, pq = (id & 31) * 4;
        int pg = Pb + pq;
        if (pg + 3 < HW) {
            float4 v = make_float4(lds[c][pq], lds[c][pq + 1], lds[c][pq + 2], lds[c][pq + 3]);
            *(float4*)(y + ((long)(b * 256 + Cb + c)) * HW + pg) = v;
        }
    }
}

// ---------------------------------------------------------------------------
extern "C" void kernel_launch(void* const* d_in, const int* in_sizes, int n_in,
                              void* d_out, int out_size, void* d_ws, size_t ws_size,
                              hipStream_t stream)
{
    const float* x     = (const float*)d_in[0];
    const float* xq_w  = (const float*)d_in[1];
    const float* xq_b  = (const float*)d_in[2];
    const float* xk_w  = (const float*)d_in[3];
    const float* xk_b  = (const float*)d_in[4];
    const float* xv_w  = (const float*)d_in[5];
    const float* xv_b  = (const float*)d_in[6];
    const float* xp_w  = (const float*)d_in[7];
    const float* xp_b  = (const float*)d_in[8];
    const float* rel_x = (const float*)d_in[9];
    const float* yq_w  = (const float*)d_in[10];
    const float* yq_b  = (const float*)d_in[11];
    const float* yk_w  = (const float*)d_in[12];
    const float* yk_b  = (const float*)d_in[13];
    const float* yv_w  = (const float*)d_in[14];
    const float* yv_b  = (const float*)d_in[15];
    const float* yp_w  = (const float*)d_in[16];
    const float* yp_b  = (const float*)d_in[17];
    const float* rel_y = (const float*)d_in[18];
    const float* cp_w  = (const float*)d_in[19];
    const float* cp_b  = (const float*)d_in[20];
    const float* m1_w  = (const float*)d_in[21];
    const float* m1_b  = (const float*)d_in[22];
    const float* m2_w  = (const float*)d_in[23];
    const float* m2_b  = (const float*)d_in[24];
    const float* ls1   = (const float*)d_in[25];
    const float* ls2   = (const float*)d_in[26];

    if (ws_size < 128450560) return;

    char* ws = (char*)d_ws;
    u16*   QKV  = (u16*)(ws + 0);            // [8][3136][1536] bf16
    u16*   Hb   = (u16*)(ws + 0);            // [8][3136][512]  bf16 (reuses dead QKV)
    float* OUTp = (float*)(ws + 25690112);   // [8][3136][256]  f32  (reuses dead QKV)
    u16*   Xt   = (u16*)(ws + 77070336);     // [8][3136][256]  bf16
    u16*   Sb   = (u16*)(ws + 89915392);     // [8][3136][512]  bf16
    u16*   NETp = (u16*)(ws + 89915392);     // [8][3136][256]  bf16 (reuses dead Sb)
    u16*   AXY  = (u16*)(ws + 115605504);    // [8][3136][256]  bf16

    dim3 blk(256, 1, 1);

    transpose_x<<<dim3(49, 4, 8), blk, 0, stream>>>(x, Xt);
    pgemm<<<dim3(25, 12, 8), blk, 0, stream>>>(xq_w, xk_w, xv_w, xq_b, xk_b, xv_b,
        Xt, 256, 0, 128, QKV, 1536, 0, 0, nullptr, nullptr, 0, 0);
    attn_kernel<<<dim3(56, 4, 8), blk, 0, stream>>>(QKV, rel_x, Sb, 0);
    pgemm<<<dim3(25, 1, 8), blk, 0, stream>>>(xp_w, nullptr, nullptr, xp_b, nullptr, nullptr,
        Sb, 512, 0, 512, AXY, 256, 0, 0, nullptr, Xt, 0, 0);
    pgemm<<<dim3(25, 12, 8), blk, 0, stream>>>(yq_w, yk_w, yv_w, yq_b, yk_b, yv_b,
        Xt, 256, 128, 128, QKV, 1536, 0, 0, nullptr, nullptr, 0, 0);
    attn_kernel<<<dim3(56, 4, 8), blk, 0, stream>>>(QKV, rel_y, Sb, 1);
    pgemm<<<dim3(25, 1, 8), blk, 0, stream>>>(yp_w, nullptr, nullptr, yp_b, nullptr, nullptr,
        Sb, 512, 0, 512, AXY, 256, 128, 0, nullptr, Xt, 128, 0);
    pgemm<<<dim3(25, 2, 8), blk, 0, stream>>>(cp_w, nullptr, nullptr, cp_b, nullptr, nullptr,
        AXY, 256, 0, 256, NETp, 256, 0, 0, ls1, Xt, 0, 0);
    pgemm<<<dim3(25, 4, 8), blk, 0, stream>>>(m1_w, nullptr, nullptr, m1_b, nullptr, nullptr,
        NETp, 256, 0, 256, Hb, 512, 0, 0, nullptr, nullptr, 0, 1);
    pgemm<<<dim3(25, 2, 8), blk, 0, stream>>>(m2_w, nullptr, nullptr, m2_b, nullptr, nullptr,
        Hb, 512, 0, 512, OUTp, 256, 0, 1, ls2, nullptr, 0, 0);
    fuse_out<<<dim3(25, 8, 8), blk, 0, stream>>>(OUTp, NETp, (float*)d_out);
}

// Round 5
// 300.981 us; speedup vs baseline: 2.4165x; 1.1962x over previous
//
#include <hip/hip_runtime.h>

using u16 = unsigned short;
using u32 = unsigned int;

typedef short bf16x8 __attribute__((ext_vector_type(8)));
typedef float f32x4 __attribute__((ext_vector_type(4)));

#define HW 3136
#define IMG 56

__device__ __forceinline__ float bf2f(u16 v) {
    union { u32 u; float f; } c; c.u = ((u32)v) << 16; return c.f;
}
__device__ __forceinline__ u16 f2bf(float f) {
    union { float f; u32 u; } c; c.f = f;
    return (u16)((c.u + 0x7fffu + ((c.u >> 16) & 1u)) >> 16);
}
// pack 2 f32 -> 2 bf16 in one u32 (RNE, hardware cvt)
__device__ __forceinline__ u32 pk2bf(float a, float b) {
    u32 r;
    asm("v_cvt_pk_bf16_f32 %0, %1, %2" : "=v"(r) : "v"(a), "v"(b));
    return r;
}
__device__ __forceinline__ int swz8(int r) { return (r ^ (r >> 3)) & 7; }

__device__ __forceinline__ f32x4 mfma16(bf16x8 a, bf16x8 b, f32x4 c) {
    return __builtin_amdgcn_mfma_f32_16x16x32_bf16(a, b, c, 0, 0, 0);
}

// async global->LDS, 16B per lane; dest = lds_base + lane*16 (wave-uniform base)
__device__ __forceinline__ void gl_lds(const void* g, void* l) {
    __builtin_amdgcn_global_load_lds((const __attribute__((address_space(1))) void*)g,
                                     (__attribute__((address_space(3))) void*)l, 16, 0, 0);
}

// ---------------------------------------------------------------------------
// wcvt: convert all weights f32->bf16 into Wb (contiguous, order below) and
// concat biases f32 into Bc.
// Wb: xq|xk|xv (196608) yq|yk|yv (196608) xp(65536) yp(65536) cp(65536)
//     m1(131072) m2(131072)   total 851968 elems
// Bc: xq|xk|xv|yq|yk|yv (3072) xp(128) yp(128) cp(256) m1(512) m2(256) = 4352
// ---------------------------------------------------------------------------
__global__ __launch_bounds__(256) void wcvt(
    const float* __restrict__ s0, const float* __restrict__ s1, const float* __restrict__ s2,
    const float* __restrict__ s3, const float* __restrict__ s4, const float* __restrict__ s5,
    const float* __restrict__ s6, const float* __restrict__ s7, const float* __restrict__ s8,
    const float* __restrict__ s9, const float* __restrict__ s10,
    const float* __restrict__ b0, const float* __restrict__ b1, const float* __restrict__ b2,
    const float* __restrict__ b3, const float* __restrict__ b4, const float* __restrict__ b5,
    const float* __restrict__ b6, const float* __restrict__ b7, const float* __restrict__ b8,
    const float* __restrict__ b9, const float* __restrict__ b10,
    u16* __restrict__ Wb, float* __restrict__ Bc)
{
    const int tid = threadIdx.x;
    if (blockIdx.x == 832) {   // biases, scalar
        for (int i = tid; i < 4352; i += 256) {
            const float* src; int off;
            if      (i < 512)  { src = b0;  off = i; }
            else if (i < 1024) { src = b1;  off = i - 512; }
            else if (i < 1536) { src = b2;  off = i - 1024; }
            else if (i < 2048) { src = b3;  off = i - 1536; }
            else if (i < 2560) { src = b4;  off = i - 2048; }
            else if (i < 3072) { src = b5;  off = i - 2560; }
            else if (i < 3200) { src = b6;  off = i - 3072; }
            else if (i < 3328) { src = b7;  off = i - 3200; }
            else if (i < 3584) { src = b8;  off = i - 3328; }
            else if (i < 4096) { src = b9;  off = i - 3584; }
            else               { src = b10; off = i - 4096; }
            Bc[i] = src[off];
        }
        return;
    }
    long gid4 = ((long)blockIdx.x * 256 + tid) * 4;
    const float* src; long off;
    if (gid4 < 589824) {
        int seg = (int)(gid4 >> 16);
        const float* tab[9] = { s0, s1, s2, s3, s4, s5, s6, s7, s8 };
        src = tab[seg]; off = gid4 - ((long)seg << 16);
    } else if (gid4 < 720896) { src = s9;  off = gid4 - 589824; }
    else                      { src = s10; off = gid4 - 720896; }
    float4 v = *(const float4*)(src + off);
    *(uint2*)(Wb + gid4) = make_uint2(pk2bf(v.x, v.y), pk2bf(v.z, v.w));
}

// ---------------------------------------------------------------------------
// transpose_x: x [b][256][HW] f32  ->  Xt [b][HW][256] bf16
// ---------------------------------------------------------------------------
__global__ __launch_bounds__(256) void transpose_x(
    const float* __restrict__ x, u16* __restrict__ Xt)
{
    __shared__ u16 lds[64][80];
    const int t = threadIdx.x;
    const int Pb = blockIdx.x * 64;
    const int Cb = blockIdx.y * 64;
    const int b  = blockIdx.z;

    #pragma unroll
    for (int q = 0; q < 4; ++q) {
        int id = t + q * 256;
        int c = id >> 4, pf = (id & 15) * 4;
        float4 v = *(const float4*)(x + ((long)(b * 256 + Cb + c)) * HW + Pb + pf);
        u16 vv[4] = { f2bf(v.x), f2bf(v.y), f2bf(v.z), f2bf(v.w) };
        #pragma unroll
        for (int j = 0; j < 4; ++j) {
            int p = pf + j;
            int cc = (((c >> 3) ^ ((p >> 2) & 7)) << 3) + (c & 7);
            lds[p][cc] = vv[j];
        }
    }
    __syncthreads();
    int p = t >> 2, cf = (t & 3) * 16;
    u16* dst = Xt + ((long)b * HW + Pb + p) * 256 + Cb + cf;
    int cc0 = ((cf >> 3) + 0) ^ ((p >> 2) & 7);
    int cc1 = ((cf >> 3) + 1) ^ ((p >> 2) & 7);
    *(uint4*)(dst + 0) = *(uint4*)&lds[p][cc0 * 8];
    *(uint4*)(dst + 8) = *(uint4*)&lds[p][cc1 * 8];
}

// ---------------------------------------------------------------------------
// pgemm: p-major GEMM for 1x1 convs, bf16 weights (pre-converted).
//   out[p][outoff+m] = sum_k W[m][k] * act[p][choff+k]   (+bias, gelu, scale, res)
// Staging: global_load_lds 16B with inverse-swizzled per-lane SOURCE address
// (linear LDS dest). MFMA (W, act) -> thread holds 4 consecutive m at fixed p.
// ---------------------------------------------------------------------------
__global__ __launch_bounds__(256) void pgemm(
    const u16* __restrict__ wb, const float* __restrict__ bias,
    const u16* __restrict__ act, int actLd, int choff, int K,
    void* __restrict__ out, int outLd, int outoff, int outF32,
    const float* __restrict__ scale, const u16* __restrict__ res, int resoff,
    int gelu)
{
    __shared__ __align__(16) char smem[32768];   // W tile 16K | act tile 16K
    const int tid = threadIdx.x;
    const int lane = tid & 63, wid = tid >> 6;
    const int l15 = lane & 15, lg = lane >> 4;

    // XCD-chunked swizzle (all grids have nwg % 8 == 0)
    const int gy = gridDim.y;
    const int nwg = gridDim.x * gy * 8;
    int bid = blockIdx.x + gridDim.x * (blockIdx.y + gy * blockIdx.z);
    int vid = (bid & 7) * (nwg >> 3) + (bid >> 3);
    int bx = vid / (gy * 8);
    int rem = vid - bx * gy * 8;
    int by = rem >> 3;
    int bz = rem & 7;

    const int Pbase = bx * 128;
    const int Mbase = by * 128;

    // per-lane staging coordinates (fixed across K-loop)
    const int srow = wid * 32 + (lane >> 3);        // + t*8
    f32x4 acc[4][4] = {};   // acc[p-tile rt][m-tile ct][m-reg]

    for (int ko = 0; ko < K; ko += 64) {
        // ---- W tile [128m][64k] via global_load_lds (bf16 source)
        #pragma unroll
        for (int t = 0; t < 4; ++t) {
            int row = srow + t * 8;
            int c = (lane & 7) ^ swz8(row);
            gl_lds(wb + (long)(Mbase + row) * K + ko + c * 8,
                   smem + wid * 4096 + t * 1024);
        }
        // ---- act tile [128p][64k] via global_load_lds (clamp OOB rows)
        #pragma unroll
        for (int t = 0; t < 4; ++t) {
            int row = srow + t * 8;
            int c = (lane & 7) ^ swz8(row);
            int pg = Pbase + row; if (pg >= HW) pg = HW - 1;
            gl_lds(act + ((long)bz * HW + pg) * actLd + choff + ko + c * 8,
                   smem + 16384 + wid * 4096 + t * 1024);
        }
        __syncthreads();

        #pragma unroll
        for (int ks = 0; ks < 2; ++ks) {
            const int ch = ks * 4 + lg;
            bf16x8 af[4], bfr[4];
            #pragma unroll
            for (int rt = 0; rt < 4; ++rt) {
                int p = (wid >> 1) * 64 + rt * 16 + l15;
                af[rt] = *(const bf16x8*)(smem + 16384 + p * 128 + ((ch ^ swz8(p)) * 16));
            }
            #pragma unroll
            for (int ct = 0; ct < 4; ++ct) {
                int m = (wid & 1) * 64 + ct * 16 + l15;
                bfr[ct] = *(const bf16x8*)(smem + m * 128 + ((ch ^ swz8(m)) * 16));
            }
            #pragma unroll
            for (int rt = 0; rt < 4; ++rt)
                #pragma unroll
                for (int ct = 0; ct < 4; ++ct)
                    acc[rt][ct] = mfma16(bfr[ct], af[rt], acc[rt][ct]);   // A=W, B=act
        }
        __syncthreads();
    }

    // ---- epilogue: thread holds 4 consecutive m (lg*4..+3) at fixed p (l15)
    #pragma unroll
    for (int rt = 0; rt < 4; ++rt) {
        int p = Pbase + (wid >> 1) * 64 + rt * 16 + l15;
        if (p >= HW) continue;
        long rowp = (long)bz * HW + p;
        #pragma unroll
        for (int ct = 0; ct < 4; ++ct) {
            int mloc = (wid & 1) * 64 + ct * 16 + lg * 4;   // local within this matrix
            int mg = Mbase + mloc;
            float4 bv = *(const float4*)(bias + mg);
            float v[4];
            #pragma unroll
            for (int j = 0; j < 4; ++j) {
                float tt = acc[rt][ct][j] + ((const float*)&bv)[j];
                if (gelu) tt = tt * 0.5f * (1.0f + erff(tt * 0.70710678118f));
                v[j] = tt;
            }
            if (scale) {
                float4 sv = *(const float4*)(scale + outoff + mg);
                v[0] *= sv.x; v[1] *= sv.y; v[2] *= sv.z; v[3] *= sv.w;
            }
            if (res) {
                ushort4 rv = *(const ushort4*)(res + rowp * 256 + resoff + mg);
                v[0] += bf2f(rv.x); v[1] += bf2f(rv.y);
                v[2] += bf2f(rv.z); v[3] += bf2f(rv.w);
            }
            long oaddr = rowp * outLd + outoff + mg;
            if (outF32) {
                *(float4*)((float*)out + oaddr) = make_float4(v[0], v[1], v[2], v[3]);
            } else {
                *(uint2*)((u16*)out + oaddr) = make_uint2(pk2bf(v[0], v[1]), pk2bf(v[2], v[3]));
            }
        }
    }
}

// ---------------------------------------------------------------------------
// Axial attention, one block per (b, row-or-col, head). 4 waves.
// ---------------------------------------------------------------------------
__global__ __launch_bounds__(256) void attn_kernel(
    const u16* __restrict__ qkv,
    const float* __restrict__ rel,
    u16* __restrict__ S, int branch)
{
    __shared__ __align__(16) char smem[57856];
    // QT:[0,16K) KT:[16K,32K) V:[32K,48K) P:[49152,57344) RELf32:[57344,57856)
    const int tid = threadIdx.x;
    const int lane = tid & 63, wid = tid >> 6;
    const int rc = blockIdx.x;
    const int n  = blockIdx.y;
    const int b  = blockIdx.z;

    if (tid < 128) {
        float v = (tid < 112) ? rel[n * HW + tid] : 0.0f;
        *(float*)(smem + 57344 + tid * 4) = v;
    }
    #pragma unroll
    for (int t = 0; t < 4; ++t)
        *(uint4*)(smem + 32768 + (tid + t * 256) * 16) = make_uint4(0, 0, 0, 0);
    __syncthreads();

    // ---- stage Qt/Kt [64][128] seq-major
    #pragma unroll
    for (int t = 0; t < 4; ++t) {
        int id = tid + t * 256;
        int i = id >> 4, c = id & 15;
        uint4 v  = make_uint4(0, 0, 0, 0);
        uint4 v2 = make_uint4(0, 0, 0, 0);
        if (i < IMG) {
            long p = (branch == 0) ? ((long)rc * IMG + i) : ((long)i * IMG + rc);
            const u16* src = qkv + ((long)b * HW + p) * 1536 + n * 128 + c * 8;
            v  = *(const uint4*)src;
            v2 = *(const uint4*)(src + 512);
        }
        int off = i * 256 + ((c ^ swz8(i)) * 16);
        *(uint4*)(smem + off) = v;
        *(uint4*)(smem + 16384 + off) = v2;
    }
    // ---- stage V [128d][64j] via small scatter transpose
    for (int id = tid; id < 896; id += 256) {
        int j = id >> 4, d0 = (id & 15) * 8;
        long p = (branch == 0) ? ((long)rc * IMG + j) : ((long)j * IMG + rc);
        const u16* src = qkv + ((long)b * HW + p) * 1536 + 1024 + n * 128 + d0;
        u16 vals[8];
        *(uint4*)vals = *(const uint4*)src;
        #pragma unroll
        for (int jj = 0; jj < 8; ++jj) {
            int d = d0 + jj;
            *(u16*)(smem + 32768 + d * 128 + (((j >> 3) ^ swz8(d)) * 16) + (j & 7) * 2) = vals[jj];
        }
    }
    __syncthreads();

    const int l15 = lane & 15, lg = lane >> 4;
    const int istrip = wid * 16;

    // ---- S = Q^T K
    bf16x8 aq[4];
    #pragma unroll
    for (int ks = 0; ks < 4; ++ks) {
        int row = istrip + l15;
        int ch = ks * 4 + lg;
        aq[ks] = *(const bf16x8*)(smem + row * 256 + ((ch ^ swz8(row)) * 16));
    }
    f32x4 sacc[4] = {};
    #pragma unroll
    for (int ct = 0; ct < 4; ++ct) {
        #pragma unroll
        for (int ks = 0; ks < 4; ++ks) {
            int j = ct * 16 + l15;
            int ch = ks * 4 + lg;
            bf16x8 kb = *(const bf16x8*)(smem + 16384 + j * 256 + ((ch ^ swz8(j)) * 16));
            sacc[ct] = mfma16(aq[ks], kb, sacc[ct]);
        }
    }

    // ---- softmax
    const float qscale = 0.08838834764831845f;
    float pv[4][4];
    #pragma unroll
    for (int ct = 0; ct < 4; ++ct)
        #pragma unroll
        for (int r = 0; r < 4; ++r) {
            int i = istrip + lg * 4 + r;
            int j = ct * 16 + l15;
            float x = sacc[ct][r] * qscale;
            if (j < IMG) x += *(const float*)(smem + 57344 + (i - j + 55) * 4);
            else x = -1e30f;
            pv[ct][r] = x;
        }
    #pragma unroll
    for (int r = 0; r < 4; ++r) {
        float mx = fmaxf(fmaxf(pv[0][r], pv[1][r]), fmaxf(pv[2][r], pv[3][r]));
        mx = fmaxf(mx, __shfl_xor(mx, 1));
        mx = fmaxf(mx, __shfl_xor(mx, 2));
        mx = fmaxf(mx, __shfl_xor(mx, 4));
        mx = fmaxf(mx, __shfl_xor(mx, 8));
        float s0 = 0.f;
        #pragma unroll
        for (int ct = 0; ct < 4; ++ct) { pv[ct][r] = expf(pv[ct][r] - mx); s0 += pv[ct][r]; }
        s0 += __shfl_xor(s0, 1); s0 += __shfl_xor(s0, 2);
        s0 += __shfl_xor(s0, 4); s0 += __shfl_xor(s0, 8);
        float inv = 1.0f / s0;
        int i = istrip + lg * 4 + r;
        #pragma unroll
        for (int ct = 0; ct < 4; ++ct) {
            int j = ct * 16 + l15;
            *(u16*)(smem + 49152 + i * 128 + (((j >> 3) ^ swz8(i)) * 16) + (j & 7) * 2) = f2bf(pv[ct][r] * inv);
        }
    }
    __syncthreads();

    // ---- O = P V^T with A=V, B=P: D rows = d, cols = i
    bf16x8 pa[2];
    #pragma unroll
    for (int ks = 0; ks < 2; ++ks) {
        int row = istrip + l15;
        int ch = ks * 4 + lg;
        pa[ks] = *(const bf16x8*)(smem + 49152 + row * 128 + ((ch ^ swz8(row)) * 16));
    }
    f32x4 oacc[8] = {};
    #pragma unroll
    for (int dt = 0; dt < 8; ++dt) {
        #pragma unroll
        for (int ks = 0; ks < 2; ++ks) {
            int d = dt * 16 + l15;
            int ch = ks * 4 + lg;
            bf16x8 vb = *(const bf16x8*)(smem + 32768 + d * 128 + ((ch ^ swz8(d)) * 16));
            oacc[dt] = mfma16(vb, pa[ks], oacc[dt]);
        }
    }

    // ---- store p-major scrambled, packed 8B
    const int i = istrip + l15;
    if (i < IMG) {
        int im = n * 14 + (i >> 2);
        long p = (branch == 0) ? ((long)rc * IMG + im) : ((long)im * IMG + rc);
        u16* dst = S + ((long)b * HW + p) * 512 + (i & 3) * 128;
        #pragma unroll
        for (int dt = 0; dt < 8; ++dt) {
            int d4 = dt * 16 + lg * 4;
            *(uint2*)(dst + d4) = make_uint2(pk2bf(oacc[dt][0], oacc[dt][1]),
                                             pk2bf(oacc[dt][2], oacc[dt][3]));
        }
    }
}

// ---------------------------------------------------------------------------
// fuse_out: d_out[b][c][p] (f32, m-major) = OUTp[b][p][c] (bf16, p-major)
// ---------------------------------------------------------------------------
__global__ __launch_bounds__(256) void fuse_out(
    const u16* __restrict__ OUTp, float* __restrict__ y)
{
    __shared__ float lds[32][132];
    const int t = threadIdx.x;
    const int Pb = blockIdx.x * 128;
    const int Cb = blockIdx.y * 32;
    const int b  = blockIdx.z;

    #pragma unroll
    for (int q = 0; q < 4; ++q) {
        int id = t + q * 256;
        int p = id >> 3, cq = (id & 7) * 4;
        int pg = Pb + p;
        float4 v = make_float4(0.f, 0.f, 0.f, 0.f);
        if (pg < HW) {
            ushort4 nv = *(const ushort4*)(OUTp + ((long)b * HW + pg) * 256 + Cb + cq);
            v.x = bf2f(nv.x); v.y = bf2f(nv.y); v.z = bf2f(nv.z); v.w = bf2f(nv.w);
        }
        lds[cq + 0][p] = v.x; lds[cq + 1][p] = v.y;
        lds[cq + 2][p] = v.z; lds[cq + 3][p] = v.w;
    }
    __syncthreads();
    #pragma unroll
    for (int q = 0; q < 4; ++q) {
        int id = t + q * 256;
        int c = id >> 5, pq = (id & 31) * 4;
        int pg = Pb + pq;
        if (pg + 3 < HW) {
            float4 v = make_float4(lds[c][pq], lds[c][pq + 1], lds[c][pq + 2], lds[c][pq + 3]);
            *(float4*)(y + ((long)(b * 256 + Cb + c)) * HW + pg) = v;
        }
    }
}

// ---------------------------------------------------------------------------
extern "C" void kernel_launch(void* const* d_in, const int* in_sizes, int n_in,
                              void* d_out, int out_size, void* d_ws, size_t ws_size,
                              hipStream_t stream)
{
    const float* x     = (const float*)d_in[0];
    const float* xq_w  = (const float*)d_in[1];
    const float* xq_b  = (const float*)d_in[2];
    const float* xk_w  = (const float*)d_in[3];
    const float* xk_b  = (const float*)d_in[4];
    const float* xv_w  = (const float*)d_in[5];
    const float* xv_b  = (const float*)d_in[6];
    const float* xp_w  = (const float*)d_in[7];
    const float* xp_b  = (const float*)d_in[8];
    const float* rel_x = (const float*)d_in[9];
    const float* yq_w  = (const float*)d_in[10];
    const float* yq_b  = (const float*)d_in[11];
    const float* yk_w  = (const float*)d_in[12];
    const float* yk_b  = (const float*)d_in[13];
    const float* yv_w  = (const float*)d_in[14];
    const float* yv_b  = (const float*)d_in[15];
    const float* yp_w  = (const float*)d_in[16];
    const float* yp_b  = (const float*)d_in[17];
    const float* rel_y = (const float*)d_in[18];
    const float* cp_w  = (const float*)d_in[19];
    const float* cp_b  = (const float*)d_in[20];
    const float* m1_w  = (const float*)d_in[21];
    const float* m1_b  = (const float*)d_in[22];
    const float* m2_w  = (const float*)d_in[23];
    const float* m2_b  = (const float*)d_in[24];
    const float* ls1   = (const float*)d_in[25];
    const float* ls2   = (const float*)d_in[26];

    if (ws_size < 128450560) return;

    char* ws = (char*)d_ws;
    u16*   QKV  = (u16*)(ws + 0);            // [8][3136][1536] bf16
    u16*   Hb   = (u16*)(ws + 0);            // [8][3136][512]  bf16 (reuses dead QKV)
    u16*   OUTp = (u16*)(ws + 25690112);     // [8][3136][256]  bf16 (reuses dead QKV)
    u16*   Xt   = (u16*)(ws + 77070336);     // [8][3136][256]  bf16
    u16*   Sb   = (u16*)(ws + 89915392);     // [8][3136][512]  bf16
    u16*   NETp = (u16*)(ws + 89915392);     // [8][3136][256]  bf16 (reuses dead Sb)
    u16*   AXY  = (u16*)(ws + 115605504);    // [8][3136][256]  bf16

    // weights/biases in d_out scratch (fully overwritten by fuse_out at the end)
    u16*   Wb = (u16*)d_out;                     // 851968 bf16 = 1,703,936 B
    float* Bc = (float*)((char*)d_out + 1703936); // 4352 f32

    dim3 blk(256, 1, 1);

    wcvt<<<dim3(833, 1, 1), blk, 0, stream>>>(
        xq_w, xk_w, xv_w, yq_w, yk_w, yv_w, xp_w, yp_w, cp_w, m1_w, m2_w,
        xq_b, xk_b, xv_b, yq_b, yk_b, yv_b, xp_b, yp_b, cp_b, m1_b, m2_b,
        Wb, Bc);
    transpose_x<<<dim3(49, 4, 8), blk, 0, stream>>>(x, Xt);
    // QKV branch X: Wb @0, Bc @0
    pgemm<<<dim3(25, 12, 8), blk, 0, stream>>>(Wb, Bc,
        Xt, 256, 0, 128, QKV, 1536, 0, 0, nullptr, nullptr, 0, 0);
    attn_kernel<<<dim3(56, 4, 8), blk, 0, stream>>>(QKV, rel_x, Sb, 0);
    // out-proj X: Wb @393216, Bc @3072
    pgemm<<<dim3(25, 1, 8), blk, 0, stream>>>(Wb + 393216, Bc + 3072,
        Sb, 512, 0, 512, AXY, 256, 0, 0, nullptr, Xt, 0, 0);
    // QKV branch Y: Wb @196608, Bc @1536
    pgemm<<<dim3(25, 12, 8), blk, 0, stream>>>(Wb + 196608, Bc + 1536,
        Xt, 256, 128, 128, QKV, 1536, 0, 0, nullptr, nullptr, 0, 0);
    attn_kernel<<<dim3(56, 4, 8), blk, 0, stream>>>(QKV, rel_y, Sb, 1);
    // out-proj Y: Wb @458752, Bc @3200
    pgemm<<<dim3(25, 1, 8), blk, 0, stream>>>(Wb + 458752, Bc + 3200,
        Sb, 512, 0, 512, AXY, 256, 128, 0, nullptr, Xt, 128, 0);
    // cp: Wb @524288, Bc @3328
    pgemm<<<dim3(25, 2, 8), blk, 0, stream>>>(Wb + 524288, Bc + 3328,
        AXY, 256, 0, 256, NETp, 256, 0, 0, ls1, Xt, 0, 0);
    // m1 + GELU: Wb @589824, Bc @3584
    pgemm<<<dim3(25, 4, 8), blk, 0, stream>>>(Wb + 589824, Bc + 3584,
        NETp, 256, 0, 256, Hb, 512, 0, 0, nullptr, nullptr, 0, 1);
    // m2, *ls2 + NET residual -> OUTp (bf16): Wb @720896, Bc @4096
    pgemm<<<dim3(25, 2, 8), blk, 0, stream>>>(Wb + 720896, Bc + 4096,
        Hb, 512, 0, 512, OUTp, 256, 0, 0, ls2, NETp, 0, 0);
    fuse_out<<<dim3(25, 8, 8), blk, 0, stream>>>(OUTp, (float*)d_out);
}

// Round 6
// 244.659 us; speedup vs baseline: 2.9728x; 1.2302x over previous
//
#include <hip/hip_runtime.h>

using u16 = unsigned short;
using u32 = unsigned int;

typedef short bf16x8 __attribute__((ext_vector_type(8)));
typedef float f32x4 __attribute__((ext_vector_type(4)));

#define HW 3136
#define IMG 56

__device__ __forceinline__ float bf2f(u16 v) {
    union { u32 u; float f; } c; c.u = ((u32)v) << 16; return c.f;
}
__device__ __forceinline__ u16 f2bf(float f) {
    union { float f; u32 u; } c; c.f = f;
    return (u16)((c.u + 0x7fffu + ((c.u >> 16) & 1u)) >> 16);
}
// pack 2 f32 -> 2 bf16 in one u32 (RNE, hardware cvt)
__device__ __forceinline__ u32 pk2bf(float a, float b) {
    u32 r;
    asm("v_cvt_pk_bf16_f32 %0, %1, %2" : "=v"(r) : "v"(a), "v"(b));
    return r;
}
__device__ __forceinline__ int swz8(int r) { return (r ^ (r >> 3)) & 7; }

__device__ __forceinline__ f32x4 mfma16(bf16x8 a, bf16x8 b, f32x4 c) {
    return __builtin_amdgcn_mfma_f32_16x16x32_bf16(a, b, c, 0, 0, 0);
}

// async global->LDS, 16B per lane; dest = lds_base + lane*16 (wave-uniform base)
__device__ __forceinline__ void gl_lds(const void* g, void* l) {
    __builtin_amdgcn_global_load_lds((const __attribute__((address_space(1))) void*)g,
                                     (__attribute__((address_space(3))) void*)l, 16, 0, 0);
}

// ---------------------------------------------------------------------------
// wcvt: convert all weights f32->bf16 into Wb and concat biases f32 into Bc.
// Wb: xq|xk|xv (196608) yq|yk|yv (196608) xp(65536) yp(65536) cp(65536)
//     m1(131072) m2(131072)   total 851968 elems
// Bc: xq|xk|xv|yq|yk|yv (3072) xp(128) yp(128) cp(256) m1(512) m2(256) = 4352
// ---------------------------------------------------------------------------
__global__ __launch_bounds__(256) void wcvt(
    const float* __restrict__ s0, const float* __restrict__ s1, const float* __restrict__ s2,
    const float* __restrict__ s3, const float* __restrict__ s4, const float* __restrict__ s5,
    const float* __restrict__ s6, const float* __restrict__ s7, const float* __restrict__ s8,
    const float* __restrict__ s9, const float* __restrict__ s10,
    const float* __restrict__ b0, const float* __restrict__ b1, const float* __restrict__ b2,
    const float* __restrict__ b3, const float* __restrict__ b4, const float* __restrict__ b5,
    const float* __restrict__ b6, const float* __restrict__ b7, const float* __restrict__ b8,
    const float* __restrict__ b9, const float* __restrict__ b10,
    u16* __restrict__ Wb, float* __restrict__ Bc)
{
    const int tid = threadIdx.x;
    if (blockIdx.x == 832) {   // biases, scalar
        for (int i = tid; i < 4352; i += 256) {
            const float* src; int off;
            if      (i < 512)  { src = b0;  off = i; }
            else if (i < 1024) { src = b1;  off = i - 512; }
            else if (i < 1536) { src = b2;  off = i - 1024; }
            else if (i < 2048) { src = b3;  off = i - 1536; }
            else if (i < 2560) { src = b4;  off = i - 2048; }
            else if (i < 3072) { src = b5;  off = i - 2560; }
            else if (i < 3200) { src = b6;  off = i - 3072; }
            else if (i < 3328) { src = b7;  off = i - 3200; }
            else if (i < 3584) { src = b8;  off = i - 3328; }
            else if (i < 4096) { src = b9;  off = i - 3584; }
            else               { src = b10; off = i - 4096; }
            Bc[i] = src[off];
        }
        return;
    }
    long gid4 = ((long)blockIdx.x * 256 + tid) * 4;
    const float* src; long off;
    if (gid4 < 589824) {
        int seg = (int)(gid4 >> 16);
        const float* tab[9] = { s0, s1, s2, s3, s4, s5, s6, s7, s8 };
        src = tab[seg]; off = gid4 - ((long)seg << 16);
    } else if (gid4 < 720896) { src = s9;  off = gid4 - 589824; }
    else                      { src = s10; off = gid4 - 720896; }
    float4 v = *(const float4*)(src + off);
    *(uint2*)(Wb + gid4) = make_uint2(pk2bf(v.x, v.y), pk2bf(v.z, v.w));
}

// ---------------------------------------------------------------------------
// transpose_x: x [b][256][HW] f32  ->  Xt [b][HW][256] bf16
// ---------------------------------------------------------------------------
__global__ __launch_bounds__(256) void transpose_x(
    const float* __restrict__ x, u16* __restrict__ Xt)
{
    __shared__ u16 lds[64][80];
    const int t = threadIdx.x;
    const int Pb = blockIdx.x * 64;
    const int Cb = blockIdx.y * 64;
    const int b  = blockIdx.z;

    #pragma unroll
    for (int q = 0; q < 4; ++q) {
        int id = t + q * 256;
        int c = id >> 4, pf = (id & 15) * 4;
        float4 v = *(const float4*)(x + ((long)(b * 256 + Cb + c)) * HW + Pb + pf);
        u16 vv[4] = { f2bf(v.x), f2bf(v.y), f2bf(v.z), f2bf(v.w) };
        #pragma unroll
        for (int j = 0; j < 4; ++j) {
            int p = pf + j;
            int cc = (((c >> 3) ^ ((p >> 2) & 7)) << 3) + (c & 7);
            lds[p][cc] = vv[j];
        }
    }
    __syncthreads();
    int p = t >> 2, cf = (t & 3) * 16;
    u16* dst = Xt + ((long)b * HW + Pb + p) * 256 + Cb + cf;
    int cc0 = ((cf >> 3) + 0) ^ ((p >> 2) & 7);
    int cc1 = ((cf >> 3) + 1) ^ ((p >> 2) & 7);
    *(uint4*)(dst + 0) = *(uint4*)&lds[p][cc0 * 8];
    *(uint4*)(dst + 8) = *(uint4*)&lds[p][cc1 * 8];
}

// ---------------------------------------------------------------------------
// pgemm: p-major GEMM for 1x1 convs, bf16 weights (pre-converted).
// ---------------------------------------------------------------------------
__global__ __launch_bounds__(256) void pgemm(
    const u16* __restrict__ wb, const float* __restrict__ bias,
    const u16* __restrict__ act, int actLd, int choff, int K,
    void* __restrict__ out, int outLd, int outoff, int outF32,
    const float* __restrict__ scale, const u16* __restrict__ res, int resoff,
    int gelu)
{
    __shared__ __align__(16) char smem[32768];   // W tile 16K | act tile 16K
    const int tid = threadIdx.x;
    const int lane = tid & 63, wid = tid >> 6;
    const int l15 = lane & 15, lg = lane >> 4;

    // XCD-chunked swizzle (all grids have nwg % 8 == 0)
    const int gy = gridDim.y;
    const int nwg = gridDim.x * gy * 8;
    int bid = blockIdx.x + gridDim.x * (blockIdx.y + gy * blockIdx.z);
    int vid = (bid & 7) * (nwg >> 3) + (bid >> 3);
    int bx = vid / (gy * 8);
    int rem = vid - bx * gy * 8;
    int by = rem >> 3;
    int bz = rem & 7;

    const int Pbase = bx * 128;
    const int Mbase = by * 128;

    const int srow = wid * 32 + (lane >> 3);        // + t*8
    f32x4 acc[4][4] = {};

    for (int ko = 0; ko < K; ko += 64) {
        #pragma unroll
        for (int t = 0; t < 4; ++t) {
            int row = srow + t * 8;
            int c = (lane & 7) ^ swz8(row);
            gl_lds(wb + (long)(Mbase + row) * K + ko + c * 8,
                   smem + wid * 4096 + t * 1024);
        }
        #pragma unroll
        for (int t = 0; t < 4; ++t) {
            int row = srow + t * 8;
            int c = (lane & 7) ^ swz8(row);
            int pg = Pbase + row; if (pg >= HW) pg = HW - 1;
            gl_lds(act + ((long)bz * HW + pg) * actLd + choff + ko + c * 8,
                   smem + 16384 + wid * 4096 + t * 1024);
        }
        __syncthreads();

        #pragma unroll
        for (int ks = 0; ks < 2; ++ks) {
            const int ch = ks * 4 + lg;
            bf16x8 af[4], bfr[4];
            #pragma unroll
            for (int rt = 0; rt < 4; ++rt) {
                int p = (wid >> 1) * 64 + rt * 16 + l15;
                af[rt] = *(const bf16x8*)(smem + 16384 + p * 128 + ((ch ^ swz8(p)) * 16));
            }
            #pragma unroll
            for (int ct = 0; ct < 4; ++ct) {
                int m = (wid & 1) * 64 + ct * 16 + l15;
                bfr[ct] = *(const bf16x8*)(smem + m * 128 + ((ch ^ swz8(m)) * 16));
            }
            #pragma unroll
            for (int rt = 0; rt < 4; ++rt)
                #pragma unroll
                for (int ct = 0; ct < 4; ++ct)
                    acc[rt][ct] = mfma16(bfr[ct], af[rt], acc[rt][ct]);   // A=W, B=act
        }
        __syncthreads();
    }

    #pragma unroll
    for (int rt = 0; rt < 4; ++rt) {
        int p = Pbase + (wid >> 1) * 64 + rt * 16 + l15;
        if (p >= HW) continue;
        long rowp = (long)bz * HW + p;
        #pragma unroll
        for (int ct = 0; ct < 4; ++ct) {
            int mloc = (wid & 1) * 64 + ct * 16 + lg * 4;
            int mg = Mbase + mloc;
            float4 bv = *(const float4*)(bias + mg);
            float v[4];
            #pragma unroll
            for (int j = 0; j < 4; ++j) {
                float tt = acc[rt][ct][j] + ((const float*)&bv)[j];
                if (gelu) tt = tt * 0.5f * (1.0f + erff(tt * 0.70710678118f));
                v[j] = tt;
            }
            if (scale) {
                float4 sv = *(const float4*)(scale + outoff + mg);
                v[0] *= sv.x; v[1] *= sv.y; v[2] *= sv.z; v[3] *= sv.w;
            }
            if (res) {
                ushort4 rv = *(const ushort4*)(res + rowp * 256 + resoff + mg);
                v[0] += bf2f(rv.x); v[1] += bf2f(rv.y);
                v[2] += bf2f(rv.z); v[3] += bf2f(rv.w);
            }
            long oaddr = rowp * outLd + outoff + mg;
            if (outF32) {
                *(float4*)((float*)out + oaddr) = make_float4(v[0], v[1], v[2], v[3]);
            } else {
                *(uint2*)((u16*)out + oaddr) = make_uint2(pk2bf(v[0], v[1]), pk2bf(v[2], v[3]));
            }
        }
    }
}

// ---------------------------------------------------------------------------
// fused_attn: QKV projection + axial attention in one kernel.
// Block = (row-group g of 7 rows, head n, branch*8+b). 4 waves.
// W fragments in VGPR (m-split: wave w owns m-tiles {2w,2w+1} of Wq/Wk/Wv),
// X fragments per-lane from global (L2). Projection writes Q/K/V straight
// into the verified swizzled LDS layouts; QK/softmax/PV/store unchanged.
// ---------------------------------------------------------------------------
__global__ __launch_bounds__(256, 1) void fused_attn(
    const u16* __restrict__ Wb, const float* __restrict__ Bc,
    const u16* __restrict__ Xt,
    const float* __restrict__ rel_x, const float* __restrict__ rel_y,
    u16* __restrict__ SbX, u16* __restrict__ SbY)
{
    __shared__ __align__(16) char smem[57856];
    // QT:[0,16K) KT:[16K,32K) V:[32K,48K) P:[49152,57344) RELf32:[57344,57856)
    const int tid = threadIdx.x;
    const int lane = tid & 63, wid = tid >> 6;
    const int l15 = lane & 15, lg = lane >> 4;
    const int g = blockIdx.x;            // row group (7 rows)
    const int n = blockIdx.y;            // head
    const int branch = blockIdx.z >> 3;
    const int b = blockIdx.z & 7;

    const float* rel = branch ? rel_y : rel_x;
    u16* S = branch ? SbY : SbX;
    const u16* wsrc = Wb + branch * 196608 + n * 16384;   // + mat*65536
    const float* bsrc = Bc + branch * 1536 + n * 128;     // + mat*512

    if (tid < 128) {
        float v = (tid < 112) ? rel[n * HW + tid] : 0.0f;
        *(float*)(smem + 57344 + tid * 4) = v;
    }

    // ---- preload W fragments (whole-block lifetime): [mat][mt][ks]
    bf16x8 wf[3][2][4];
    #pragma unroll
    for (int mat = 0; mat < 3; ++mat)
        #pragma unroll
        for (int mt = 0; mt < 2; ++mt) {
            int mrow = (wid * 2 + mt) * 16 + l15;
            const u16* wr = wsrc + mat * 65536 + mrow * 128;
            #pragma unroll
            for (int ks = 0; ks < 4; ++ks)
                wf[mat][mt][ks] = *(const bf16x8*)(wr + (ks * 4 + lg) * 8);
        }
    // ---- biases
    float4 bq4[2], bk4[2]; float bvv[2];
    #pragma unroll
    for (int mt = 0; mt < 2; ++mt) {
        int m0 = (wid * 2 + mt) * 16 + lg * 4;
        bq4[mt] = *(const float4*)(bsrc + m0);
        bk4[mt] = *(const float4*)(bsrc + 512 + m0);
        bvv[mt] = bsrc[1024 + (wid * 2 + mt) * 16 + l15];
    }

    const int istrip = wid * 16;

    for (int r = 0; r < 7; ++r) {
        const int rc = g * 7 + r;

        // ---- X fragments from global (row i on l15, k-chunk on lg)
        bf16x8 xf[4][4];
        #pragma unroll
        for (int it = 0; it < 4; ++it) {
            int i = it * 16 + l15; if (i > 55) i = 55;
            long p = (branch == 0) ? (long)rc * IMG + i : (long)i * IMG + rc;
            const u16* xr = Xt + ((long)b * HW + p) * 256 + branch * 128;
            #pragma unroll
            for (int ks = 0; ks < 4; ++ks)
                xf[it][ks] = *(const bf16x8*)(xr + (ks * 4 + lg) * 8);
        }
        __syncthreads();   // previous row's LDS reads done

        // ---- Q (mat0), K (mat1): D[m][i], store into QT/KT
        #pragma unroll
        for (int mat = 0; mat < 2; ++mat) {
            #pragma unroll
            for (int mt = 0; mt < 2; ++mt) {
                #pragma unroll
                for (int it = 0; it < 4; ++it) {
                    f32x4 a = {};
                    #pragma unroll
                    for (int ks = 0; ks < 4; ++ks)
                        a = mfma16(wf[mat][mt][ks], xf[it][ks], a);
                    int i = it * 16 + l15;
                    int m0 = (wid * 2 + mt) * 16 + lg * 4;
                    float4 bb = mat ? bk4[mt] : bq4[mt];
                    int c = m0 >> 3;
                    *(uint2*)(smem + mat * 16384 + i * 256 + ((c ^ swz8(i)) * 16) + (lg & 1) * 8)
                        = make_uint2(pk2bf(a[0] + bb.x, a[1] + bb.y),
                                     pk2bf(a[2] + bb.z, a[3] + bb.w));
                }
            }
        }
        // ---- V (mat2): D[i][d], store into VT [128d][64j]
        #pragma unroll
        for (int mt = 0; mt < 2; ++mt) {
            #pragma unroll
            for (int it = 0; it < 4; ++it) {
                f32x4 a = {};
                #pragma unroll
                for (int ks = 0; ks < 4; ++ks)
                    a = mfma16(xf[it][ks], wf[2][mt][ks], a);
                int d = (wid * 2 + mt) * 16 + l15;
                int i0 = it * 16 + lg * 4;
                float bv = bvv[mt];
                int cj = i0 >> 3;
                *(uint2*)(smem + 32768 + d * 128 + ((cj ^ swz8(d)) * 16) + (lg & 1) * 8)
                    = make_uint2(pk2bf(a[0] + bv, a[1] + bv),
                                 pk2bf(a[2] + bv, a[3] + bv));
            }
        }
        __syncthreads();

        // ---- S = Q^T K
        bf16x8 aq[4];
        #pragma unroll
        for (int ks = 0; ks < 4; ++ks) {
            int row = istrip + l15;
            int ch = ks * 4 + lg;
            aq[ks] = *(const bf16x8*)(smem + row * 256 + ((ch ^ swz8(row)) * 16));
        }
        f32x4 sacc[4] = {};
        #pragma unroll
        for (int ct = 0; ct < 4; ++ct) {
            #pragma unroll
            for (int ks = 0; ks < 4; ++ks) {
                int j = ct * 16 + l15;
                int ch = ks * 4 + lg;
                bf16x8 kb = *(const bf16x8*)(smem + 16384 + j * 256 + ((ch ^ swz8(j)) * 16));
                sacc[ct] = mfma16(aq[ks], kb, sacc[ct]);
            }
        }

        // ---- softmax
        const float qscale = 0.08838834764831845f;
        float pv[4][4];
        #pragma unroll
        for (int ct = 0; ct < 4; ++ct)
            #pragma unroll
            for (int rr = 0; rr < 4; ++rr) {
                int i = istrip + lg * 4 + rr;
                int j = ct * 16 + l15;
                float x = sacc[ct][rr] * qscale;
                if (j < IMG) x += *(const float*)(smem + 57344 + (i - j + 55) * 4);
                else x = -1e30f;
                pv[ct][rr] = x;
            }
        #pragma unroll
        for (int rr = 0; rr < 4; ++rr) {
            float mx = fmaxf(fmaxf(pv[0][rr], pv[1][rr]), fmaxf(pv[2][rr], pv[3][rr]));
            mx = fmaxf(mx, __shfl_xor(mx, 1));
            mx = fmaxf(mx, __shfl_xor(mx, 2));
            mx = fmaxf(mx, __shfl_xor(mx, 4));
            mx = fmaxf(mx, __shfl_xor(mx, 8));
            float s0 = 0.f;
            #pragma unroll
            for (int ct = 0; ct < 4; ++ct) { pv[ct][rr] = expf(pv[ct][rr] - mx); s0 += pv[ct][rr]; }
            s0 += __shfl_xor(s0, 1); s0 += __shfl_xor(s0, 2);
            s0 += __shfl_xor(s0, 4); s0 += __shfl_xor(s0, 8);
            float inv = 1.0f / s0;
            int i = istrip + lg * 4 + rr;
            #pragma unroll
            for (int ct = 0; ct < 4; ++ct) {
                int j = ct * 16 + l15;
                *(u16*)(smem + 49152 + i * 128 + (((j >> 3) ^ swz8(i)) * 16) + (j & 7) * 2) = f2bf(pv[ct][rr] * inv);
            }
        }
        __syncthreads();

        // ---- O = P V^T with A=V, B=P: thread holds 4 consecutive d at fixed i
        bf16x8 pa[2];
        #pragma unroll
        for (int ks = 0; ks < 2; ++ks) {
            int row = istrip + l15;
            int ch = ks * 4 + lg;
            pa[ks] = *(const bf16x8*)(smem + 49152 + row * 128 + ((ch ^ swz8(row)) * 16));
        }
        f32x4 oacc[8] = {};
        #pragma unroll
        for (int dt = 0; dt < 8; ++dt) {
            #pragma unroll
            for (int ks = 0; ks < 2; ++ks) {
                int d = dt * 16 + l15;
                int ch = ks * 4 + lg;
                bf16x8 vb = *(const bf16x8*)(smem + 32768 + d * 128 + ((ch ^ swz8(d)) * 16));
                oacc[dt] = mfma16(vb, pa[ks], oacc[dt]);
            }
        }

        // ---- store p-major scrambled Sb, packed 8B
        const int i = istrip + l15;
        if (i < IMG) {
            int im = n * 14 + (i >> 2);
            long p = (branch == 0) ? (long)rc * IMG + im : (long)im * IMG + rc;
            u16* dst = S + ((long)b * HW + p) * 512 + (i & 3) * 128;
            #pragma unroll
            for (int dt = 0; dt < 8; ++dt) {
                int d4 = dt * 16 + lg * 4;
                *(uint2*)(dst + d4) = make_uint2(pk2bf(oacc[dt][0], oacc[dt][1]),
                                                 pk2bf(oacc[dt][2], oacc[dt][3]));
            }
        }
    }
}

// ---------------------------------------------------------------------------
// fuse_out: d_out[b][c][p] (f32, m-major) = OUTp[b][p][c] (bf16, p-major)
// ---------------------------------------------------------------------------
__global__ __launch_bounds__(256) void fuse_out(
    const u16* __restrict__ OUTp, float* __restrict__ y)
{
    __shared__ float lds[32][132];
    const int t = threadIdx.x;
    const int Pb = blockIdx.x * 128;
    const int Cb = blockIdx.y * 32;
    const int b  = blockIdx.z;

    #pragma unroll
    for (int q = 0; q < 4; ++q) {
        int id = t + q * 256;
        int p = id >> 3, cq = (id & 7) * 4;
        int pg = Pb + p;
        float4 v = make_float4(0.f, 0.f, 0.f, 0.f);
        if (pg < HW) {
            ushort4 nv = *(const ushort4*)(OUTp + ((long)b * HW + pg) * 256 + Cb + cq);
            v.x = bf2f(nv.x); v.y = bf2f(nv.y); v.z = bf2f(nv.z); v.w = bf2f(nv.w);
        }
        lds[cq + 0][p] = v.x; lds[cq + 1][p] = v.y;
        lds[cq + 2][p] = v.z; lds[cq + 3][p] = v.w;
    }
    __syncthreads();
    #pragma unroll
    for (int q = 0; q < 4; ++q) {
        int id = t + q * 256;
        int c = id >> 5, pq = (id & 31) * 4;
        int pg = Pb + pq;
        if (pg + 3 < HW) {
            float4 v = make_float4(lds[c][pq], lds[c][pq + 1], lds[c][pq + 2], lds[c][pq + 3]);
            *(float4*)(y + ((long)(b * 256 + Cb + c)) * HW + pg) = v;
        }
    }
}

// ---------------------------------------------------------------------------
extern "C" void kernel_launch(void* const* d_in, const int* in_sizes, int n_in,
                              void* d_out, int out_size, void* d_ws, size_t ws_size,
                              hipStream_t stream)
{
    const float* x     = (const float*)d_in[0];
    const float* xq_w  = (const float*)d_in[1];
    const float* xq_b  = (const float*)d_in[2];
    const float* xk_w  = (const float*)d_in[3];
    const float* xk_b  = (const float*)d_in[4];
    const float* xv_w  = (const float*)d_in[5];
    const float* xv_b  = (const float*)d_in[6];
    const float* xp_w  = (const float*)d_in[7];
    const float* xp_b  = (const float*)d_in[8];
    const float* rel_x = (const float*)d_in[9];
    const float* yq_w  = (const float*)d_in[10];
    const float* yq_b  = (const float*)d_in[11];
    const float* yk_w  = (const float*)d_in[12];
    const float* yk_b  = (const float*)d_in[13];
    const float* yv_w  = (const float*)d_in[14];
    const float* yv_b  = (const float*)d_in[15];
    const float* yp_w  = (const float*)d_in[16];
    const float* yp_b  = (const float*)d_in[17];
    const float* rel_y = (const float*)d_in[18];
    const float* cp_w  = (const float*)d_in[19];
    const float* cp_b  = (const float*)d_in[20];
    const float* m1_w  = (const float*)d_in[21];
    const float* m1_b  = (const float*)d_in[22];
    const float* m2_w  = (const float*)d_in[23];
    const float* m2_b  = (const float*)d_in[24];
    const float* ls1   = (const float*)d_in[25];
    const float* ls2   = (const float*)d_in[26];

    if (ws_size < 128450560) return;

    char* ws = (char*)d_ws;
    u16*   SbY  = (u16*)(ws + 0);            // [8][3136][512] bf16 (25,690,112 B)
    u16*   Hb   = (u16*)(ws + 0);            // [8][3136][512] bf16 (after SbY dead)
    u16*   OUTp = (u16*)(ws + 25690112);     // [8][3136][256] bf16
    u16*   Xt   = (u16*)(ws + 77070336);     // [8][3136][256] bf16
    u16*   SbX  = (u16*)(ws + 89915392);     // [8][3136][512] bf16
    u16*   NETp = (u16*)(ws + 89915392);     // [8][3136][256] bf16 (after SbX dead)
    u16*   AXY  = (u16*)(ws + 115605504);    // [8][3136][256] bf16

    // weights/biases in d_out scratch (fully overwritten by fuse_out at the end)
    u16*   Wb = (u16*)d_out;                      // 851968 bf16 = 1,703,936 B
    float* Bc = (float*)((char*)d_out + 1703936); // 4352 f32

    dim3 blk(256, 1, 1);

    wcvt<<<dim3(833, 1, 1), blk, 0, stream>>>(
        xq_w, xk_w, xv_w, yq_w, yk_w, yv_w, xp_w, yp_w, cp_w, m1_w, m2_w,
        xq_b, xk_b, xv_b, yq_b, yk_b, yv_b, xp_b, yp_b, cp_b, m1_b, m2_b,
        Wb, Bc);
    transpose_x<<<dim3(49, 4, 8), blk, 0, stream>>>(x, Xt);
    // fused QKV projection + attention, both branches
    fused_attn<<<dim3(8, 4, 16), blk, 0, stream>>>(Wb, Bc, Xt, rel_x, rel_y, SbX, SbY);
    // out-proj X: Wb @393216, Bc @3072
    pgemm<<<dim3(25, 1, 8), blk, 0, stream>>>(Wb + 393216, Bc + 3072,
        SbX, 512, 0, 512, AXY, 256, 0, 0, nullptr, Xt, 0, 0);
    // out-proj Y: Wb @458752, Bc @3200
    pgemm<<<dim3(25, 1, 8), blk, 0, stream>>>(Wb + 458752, Bc + 3200,
        SbY, 512, 0, 512, AXY, 256, 128, 0, nullptr, Xt, 128, 0);
    // cp: Wb @524288, Bc @3328
    pgemm<<<dim3(25, 2, 8), blk, 0, stream>>>(Wb + 524288, Bc + 3328,
        AXY, 256, 0, 256, NETp, 256, 0, 0, ls1, Xt, 0, 0);
    // m1 + GELU: Wb @589824, Bc @3584
    pgemm<<<dim3(25, 4, 8), blk, 0, stream>>>(Wb + 589824, Bc + 3584,
        NETp, 256, 0, 256, Hb, 512, 0, 0, nullptr, nullptr, 0, 1);
    // m2, *ls2 + NET residual -> OUTp (bf16): Wb @720896, Bc @4096
    pgemm<<<dim3(25, 2, 8), blk, 0, stream>>>(Wb + 720896, Bc + 4096,
        Hb, 512, 0, 512, OUTp, 256, 0, 0, ls2, NETp, 0, 0);
    fuse_out<<<dim3(25, 8, 8), blk, 0, stream>>>(OUTp, (float*)d_out);
}